// Round 6
// baseline (1051.562 us; speedup 1.0000x reference)
//
#include <hip/hip_runtime.h>
#include <hip/hip_bf16.h>

// HGT layer: N=50000, E=400000, D=256, T=3, R=6, H=4, DK=64.
// Round 11: R10 structure with the phase-0 staging bug FIXED (each thread
// now loads/stores all 4 uint4 chunks of its 32-u16 q-row span; R10 only
// moved 2 and misplaced one -> half-garbage qrelL -> absmax 0.297).
//  - rel_msg linearity: aggregate raw vb, transform per-(dst,r) sum (ph C).
//  - qrel computed in-block from qb via MTa MFMA (ph 0.5), LDS-resident.
//  - f32 tacc + atomicAdd -> all 6 relations in ONE k2k4 launch grid(1563,6).

#define NN 50000
#define EE 400000
#define TN 3
#define RN 6
#define HN 4
#define SS (NN * RN)
#define NCHUNK 293   // ceil(SS/1024)
#define CD 32        // dsts per k2k4 block

typedef __hip_bfloat16 bf16;
typedef unsigned short u16;
using bf16x8 = __attribute__((ext_vector_type(8))) __bf16;
using f32x4  = __attribute__((ext_vector_type(4))) float;

__device__ __forceinline__ float b2f(bf16 h) { return __bfloat162float(h); }
__device__ __forceinline__ float busf(u16 u) { return __uint_as_float((unsigned)u << 16); }
__device__ __forceinline__ float blo(unsigned u) { return __uint_as_float(u << 16); }
__device__ __forceinline__ float bhi(unsigned u) { return __uint_as_float(u & 0xffff0000u); }
__device__ __forceinline__ u16 f2us(float f) {   // f32 -> bf16 bits, RNE
    unsigned u = __float_as_uint(f);
    return (u16)((u + 0x7fffu + ((u >> 16) & 1u)) >> 16);
}
__device__ __forceinline__ float ld(const void* p, long i, int f) {
    return f ? ((const float*)p)[i] : b2f(((const bf16*)p)[i]);
}

// ---------------- input dtype sniffer (f32 vs bf16 buffers) ----------------
__global__ __launch_bounds__(256) void detect_dtype(const void* __restrict__ x,
                                                    int* __restrict__ flag) {
    __shared__ int cnt_s;
    if (threadIdx.x == 0) cnt_s = 0;
    __syncthreads();
    const u16* p = (const u16*)x;
    int c = 0;
    for (int i = threadIdx.x; i < 8192; i += 256) {
        int expo = (p[i] >> 7) & 0xFF;
        if (expo >= 0x97) ++c;
    }
    atomicAdd(&cnt_s, c);
    __syncthreads();
    if (threadIdx.x == 0) *flag = (cnt_s > 64) ? 1 : 0;
}

// ---------------- merged prep: transM + transW + convertX + bucket + count ----------------
__global__ __launch_bounds__(256) void prep(const void* __restrict__ rel_att,
        const void* __restrict__ rel_msg,
        const void* __restrict__ Wk, const void* __restrict__ Wq,
        const void* __restrict__ Wv, const void* __restrict__ Wa,
        const void* __restrict__ x, const int* __restrict__ node_type,
        const int* __restrict__ edst, const int* __restrict__ etype,
        const int* __restrict__ flag,
        u16* __restrict__ MTa, u16* __restrict__ MTm,
        u16* __restrict__ WallT, u16* __restrict__ WaT,
        u16* __restrict__ xb,
        int* __restrict__ lists, int* __restrict__ cnts,
        unsigned* __restrict__ cnt) {
    int b = blockIdx.x;
    int t = threadIdx.x;
    if (b < 48) {
        int f = *flag;
        int m = b;                 // 0..23 att copy, 24..47 msg transpose
        long base = (long)(m % 24) * 4096;
        if (m < 24) {
            for (int it = 0; it < 16; ++it) {
                int idx = it * 256 + t;
                MTa[base + idx] = f2us(ld(rel_att, base + idx, f));
            }
        } else {
            for (int it = 0; it < 16; ++it) {
                int idx = it * 256 + t;
                int d = idx >> 6, j = idx & 63;
                MTm[base + (j << 6) + d] = f2us(ld(rel_msg, base + idx, f));
            }
        }
    } else if (b < 3120) {
        int f = *flag;
        int m = b - 48;            // 0..2303 WallT rows, 2304..3071 WaT rows
        if (m < 2304) {
            int ty = m / 768, o3 = m % 768;
            int sec = o3 >> 8, o = o3 & 255;
            const void* W = (sec == 0) ? Wk : (sec == 1) ? Wq : Wv;
            WallT[(size_t)ty * 768 * 256 + (size_t)o3 * 256 + t] =
                f2us(ld(W, (long)ty * 65536 + (long)t * 256 + o, f));
        } else {
            int mm = m - 2304;
            int ty = mm / 256, o = mm % 256;
            WaT[(size_t)ty * 65536 + (size_t)o * 256 + t] =
                f2us(ld(Wa, (long)ty * 65536 + (long)t * 256 + o, f));
        }
    } else if (b < 15620) {
        int f = *flag;
        long i = ((long)(b - 3120) * 256 + t) * 4;
        if (i < (long)NN * 256) {
            if (f) {
                float4 v = *(const float4*)((const float*)x + i);
                ushort4 p; p.x = f2us(v.x); p.y = f2us(v.y); p.z = f2us(v.z); p.w = f2us(v.w);
                *(ushort4*)(xb + i) = p;
            } else {
                *(ushort4*)(xb + i) = *(const ushort4*)((const u16*)x + i);
            }
        }
    } else if (b < 15816) {
        __shared__ int lc[TN], lbase[TN];
        if (t < TN) lc[t] = 0;
        __syncthreads();
        int n = (b - 15620) * 256 + t;
        int pos = -1, ty = 0;
        if (n < NN) {
            ty = node_type[n];
            pos = atomicAdd(&lc[ty], 1);
        }
        __syncthreads();
        if (t < TN) lbase[t] = atomicAdd(&cnts[t], lc[t]);
        __syncthreads();
        if (n < NN) lists[ty * NN + lbase[ty] + pos] = n;
    } else {
        int e = (b - 15816) * 256 + t;
        if (e < EE) atomicAdd(&cnt[etype[e] * NN + edst[e]], 1u);
    }
}

// ---------------- 3-phase exclusive scan over SS segments ----------------
__global__ __launch_bounds__(256) void scanA(const unsigned* __restrict__ cnt,
                                             unsigned* __restrict__ csums) {
    __shared__ unsigned s[256];
    int b = blockIdx.x, t = threadIdx.x;
    int s0 = b * 1024 + t * 4;
    unsigned v = 0;
    if (s0 + 3 < SS) { uint4 u = *(const uint4*)&cnt[s0]; v = u.x + u.y + u.z + u.w; }
    else { for (int j = 0; j < 4; ++j) if (s0 + j < SS) v += cnt[s0 + j]; }
    s[t] = v;
    __syncthreads();
    for (int st = 128; st > 0; st >>= 1) {
        if (t < st) s[t] += s[t + st];
        __syncthreads();
    }
    if (t == 0) csums[b] = s[0];
}

__global__ __launch_bounds__(256) void scanB(unsigned* __restrict__ csums,
                                             int* __restrict__ base) {
    __shared__ unsigned s[512];
    int t = threadIdx.x;
    unsigned a = (t < NCHUNK) ? csums[t] : 0u;
    unsigned b = (256 + t < NCHUNK) ? csums[256 + t] : 0u;
    s[t] = a; s[256 + t] = b;
    __syncthreads();
    for (int st = 1; st < 512; st <<= 1) {
        unsigned x0 = (t >= st) ? s[t - st] : 0u;
        unsigned x1 = (256 + t >= st) ? s[256 + t - st] : 0u;
        __syncthreads();
        s[t] += x0; s[256 + t] += x1;
        __syncthreads();
    }
    if (t < NCHUNK) csums[t] = s[t] - a;
    if (256 + t < NCHUNK) csums[256 + t] = s[256 + t] - b;
    if (t == 0) base[SS] = (int)s[NCHUNK - 1];
}

__global__ __launch_bounds__(256) void scanC(const unsigned* __restrict__ cnt,
        const unsigned* __restrict__ csums, int* __restrict__ base) {
    __shared__ unsigned s[256];
    int b = blockIdx.x, t = threadIdx.x;
    int s0 = b * 1024 + t * 4;
    unsigned vs[4] = {0u, 0u, 0u, 0u};
    if (s0 + 3 < SS) { uint4 u = *(const uint4*)&cnt[s0]; vs[0]=u.x; vs[1]=u.y; vs[2]=u.z; vs[3]=u.w; }
    else { for (int j = 0; j < 4; ++j) if (s0 + j < SS) vs[j] = cnt[s0 + j]; }
    unsigned v = vs[0] + vs[1] + vs[2] + vs[3];
    s[t] = v;
    __syncthreads();
    for (int st = 1; st < 256; st <<= 1) {
        unsigned x = (t >= st) ? s[t - st] : 0u;
        __syncthreads();
        s[t] += x;
        __syncthreads();
    }
    unsigned run = csums[b] + s[t] - v;
    for (int j = 0; j < 4; ++j) {
        if (s0 + j < SS) { base[s0 + j] = (int)run; run += vs[j]; }
    }
}

// ---------------- scatter edges into seg-sorted order (consumes cnt) ----------------
__global__ __launch_bounds__(256) void scatter_edges(const int* __restrict__ edst,
        const int* __restrict__ etype, const int* __restrict__ base,
        unsigned* __restrict__ cnt, int* __restrict__ sorted) {
    int e = blockIdx.x * 256 + threadIdx.x;
    if (e >= EE) return;
    int seg = etype[e] * NN + edst[e];
    unsigned old = atomicSub(&cnt[seg], 1u);
    sorted[base[seg] + (int)old - 1] = e;
}

// ---------------- k/q/v typed linear via MFMA (64 same-type nodes / block) ----------------
__global__ __launch_bounds__(512, 2) void k1_mfma(const u16* __restrict__ xb,
        const u16* __restrict__ WallT,
        const void* __restrict__ bk, const void* __restrict__ bq,
        const void* __restrict__ bv,
        const int* __restrict__ lists, const int* __restrict__ cnts,
        const int* __restrict__ flag,
        u16* __restrict__ kb, u16* __restrict__ qb, u16* __restrict__ vb) {
    int f = *flag;
    int tt = blockIdx.x % TN, tile = blockIdx.x / TN;
    int cnt = cnts[tt];
    int start = tile * 64;
    if (start >= cnt) return;
    __shared__ int nl[64];
    __shared__ __align__(16) u16 xs[64][280];
    __shared__ __align__(16) float bias_s[768];
    int t = threadIdx.x;
    if (t < 64) nl[t] = (start + t < cnt) ? lists[tt * NN + start + t] : -1;
    if (t < 256) {
        bias_s[t]       = ld(bk, tt * 256 + t, f);
        bias_s[256 + t] = ld(bq, tt * 256 + t, f);
        bias_s[512 + t] = ld(bv, tt * 256 + t, f);
    }
    __syncthreads();
    {
        int i = t >> 4, g = t & 15;
        #pragma unroll
        for (int i2 = 0; i2 < 2; ++i2) {
            int row = i + i2 * 32;
            int node = nl[row];
            uint4 a = {0, 0, 0, 0}, b = {0, 0, 0, 0};
            if (node >= 0) {
                const uint4* src = (const uint4*)(xb + (size_t)node * 256 + g * 16);
                a = src[0]; b = src[1];
            }
            *(uint4*)&xs[row][g * 16] = a;
            *(uint4*)&xs[row][g * 16 + 8] = b;
        }
    }
    __syncthreads();
    int w = t >> 6, lane = t & 63, ln = lane & 15, quad = lane >> 4;
    const u16* Wt = WallT + (size_t)tt * 768 * 256;
    f32x4 acc[6][4];
    #pragma unroll
    for (int j = 0; j < 6; ++j)
        #pragma unroll
        for (int g = 0; g < 4; ++g)
            acc[j][g] = (f32x4){0.f, 0.f, 0.f, 0.f};
    for (int kt = 0; kt < 8; ++kt) {
        bf16x8 A[6];
        #pragma unroll
        for (int jt = 0; jt < 6; ++jt)
            A[jt] = *(const bf16x8*)(Wt + (size_t)(w * 96 + jt * 16 + ln) * 256 + kt * 32 + quad * 8);
        bf16x8 B[4];
        #pragma unroll
        for (int g = 0; g < 4; ++g)
            B[g] = *(const bf16x8*)&xs[g * 16 + ln][kt * 32 + quad * 8];
        #pragma unroll
        for (int jt = 0; jt < 6; ++jt)
            #pragma unroll
            for (int g = 0; g < 4; ++g)
                acc[jt][g] = __builtin_amdgcn_mfma_f32_16x16x32_bf16(A[jt], B[g], acc[jt][g], 0, 0, 0);
    }
    #pragma unroll
    for (int jt = 0; jt < 6; ++jt) {
        int jc = w * 96 + jt * 16 + quad * 4;
        float4 bi = *(const float4*)&bias_s[jc];
        int sec = jc >> 8, o = jc & 255;
        u16* basep = (sec == 0 ? kb : sec == 1 ? qb : vb);
        #pragma unroll
        for (int g = 0; g < 4; ++g) {
            int node = nl[g * 16 + ln];
            if (node >= 0) {
                ushort4 p;
                p.x = f2us(acc[jt][g][0] + bi.x); p.y = f2us(acc[jt][g][1] + bi.y);
                p.z = f2us(acc[jt][g][2] + bi.z); p.w = f2us(acc[jt][g][3] + bi.w);
                *(ushort4*)(basep + (size_t)node * 256 + o) = p;
            }
        }
    }
}

// ---------------- fused attention + aggregation, ALL relations ----------------
// grid (ceil(NN/CD), RN); block = CD consecutive dsts for relation r.
__global__ __launch_bounds__(256) void k2k4(const u16* __restrict__ kb,
        const u16* __restrict__ qb, const u16* __restrict__ vb,
        const u16* __restrict__ MTa, const u16* __restrict__ MTm,
        const void* __restrict__ rel_pri,
        const int* __restrict__ sorted, const int* __restrict__ base,
        const int* __restrict__ esrc, const int* __restrict__ edst,
        const int* __restrict__ flag,
        u16* __restrict__ attex_g, float* __restrict__ tacc) {
    int f = *flag;
    int r = blockIdx.y;
    int c0 = blockIdx.x * CD;
    int nd = min(CD, NN - c0);
    int segb = r * NN + c0;
    __shared__ float attL[1280];
    __shared__ int srcL[1280];
    __shared__ float denomL[CD * HN];
    __shared__ int sb_[CD + 1];
    __shared__ __align__(16) u16 qrelL[CD][264];
    __shared__ __align__(16) u16 qsraw[CD][264];   // q staging, then raw-sum
    int t = threadIdx.x;
    int w = t >> 6, lane = t & 63, ln = lane & 15, quad = lane >> 4;
    if (t < CD * HN) denomL[t] = 0.f;
    if (t <= nd) sb_[t] = base[segb + t];
    // phase 0: gather this block's 32 q rows (512B each) into LDS
    // (4 x uint4 per thread: the R10 bug was 2 loads with a +16 store stride)
    {
        int i = t >> 3, g8 = t & 7;
        uint4 a0 = {0,0,0,0}, a1 = {0,0,0,0}, a2 = {0,0,0,0}, a3 = {0,0,0,0};
        if (i < nd) {
            const uint4* src = (const uint4*)(qb + (size_t)(c0 + i) * 256 + g8 * 32);
            a0 = src[0]; a1 = src[1]; a2 = src[2]; a3 = src[3];
        }
        *(uint4*)&qsraw[i][g8 * 32 +  0] = a0;
        *(uint4*)&qsraw[i][g8 * 32 +  8] = a1;
        *(uint4*)&qsraw[i][g8 * 32 + 16] = a2;
        *(uint4*)&qsraw[i][g8 * 32 + 24] = a3;
    }
    __syncthreads();
    // phase 0.5: qrelL[n][h*64+d] = sum_e rel_att[r,h,d,e] * q[n][h*64+e]; wave = head
    {
        long mtbase = (long)(r * HN + w) * 4096;
        #pragma unroll
        for (int grp = 0; grp < 2; ++grp) {
            int li = grp * 16 + ln;
            bf16x8 B0 = *(const bf16x8*)&qsraw[li][w * 64 + quad * 8];
            bf16x8 B1 = *(const bf16x8*)&qsraw[li][w * 64 + quad * 8 + 32];
            #pragma unroll
            for (int mt = 0; mt < 4; ++mt) {
                const u16* ap = MTa + mtbase + (mt * 16 + ln) * 64 + quad * 8;
                bf16x8 A0 = *(const bf16x8*)(ap);
                bf16x8 A1 = *(const bf16x8*)(ap + 32);
                f32x4 acc = {0.f, 0.f, 0.f, 0.f};
                acc = __builtin_amdgcn_mfma_f32_16x16x32_bf16(A0, B0, acc, 0, 0, 0);
                acc = __builtin_amdgcn_mfma_f32_16x16x32_bf16(A1, B1, acc, 0, 0, 0);
                int jc = w * 64 + mt * 16 + quad * 4;
                ushort4 pq;
                pq.x = f2us(acc[0]); pq.y = f2us(acc[1]);
                pq.z = f2us(acc[2]); pq.w = f2us(acc[3]);
                *(ushort4*)&qrelL[li][jc] = pq;
            }
        }
    }
    __syncthreads();
    int b0 = sb_[0], b1 = sb_[nd];
    int nE = b1 - b0;
    // phase A: att logits -> exp (thread per edge-head)
    for (int i = t; i < nE * 4; i += 256) {
        int ei = i >> 2;
        int e = sorted[b0 + ei];
        int h = i & 3;
        int s = esrc[e], dv = edst[e] - c0;
        if (h == 0 && ei < 1280) srcL[ei] = s;
        const uint4* kp = (const uint4*)(kb + (size_t)s * 256 + h * 64);
        const uint4* qp = (const uint4*)&qrelL[dv][h * 64];
        float dot = 0.f;
        #pragma unroll
        for (int ii = 0; ii < 8; ++ii) {
            uint4 a = kp[ii], b = qp[ii];
            dot += blo(a.x) * blo(b.x) + bhi(a.x) * bhi(b.x);
            dot += blo(a.y) * blo(b.y) + bhi(a.y) * bhi(b.y);
            dot += blo(a.z) * blo(b.z) + bhi(a.z) * bhi(b.z);
            dot += blo(a.w) * blo(b.w) + bhi(a.w) * bhi(b.w);
        }
        float attv = dot * ld(rel_pri, r * HN + h, f) * 0.125f;
        attv = fminf(fmaxf(attv, -50.f), 50.f);
        float ex = expf(attv);
        if (i < 1280) attL[i] = ex;
        else attex_g[(size_t)b0 * 4 + i] = f2us(ex);   // statistical never-path
        atomicAdd(&denomL[dv * HN + h], ex);
    }
    __syncthreads();
    // phase B: raw weighted vb sums -> sraw (wave per dst, lane = 4 dims)
    for (int i2 = w; i2 < nd; i2 += 4) {
        int sb = sb_[i2], se = sb_[i2 + 1];
        float a0 = 0.f, a1 = 0.f, a2 = 0.f, a3 = 0.f;
        if (se > sb) {
            int h = lane >> 4;
            float inv = 1.f / denomL[i2 * HN + h];
            for (int idx = sb; idx < se; ++idx) {
                int rel = idx - b0;
                int li2 = rel * 4 + h;
                float wgt = ((li2 < 1280) ? attL[li2] : busf(attex_g[(size_t)idx * 4 + h])) * inv;
                int s = (rel < 1280) ? srcL[rel] : esrc[sorted[idx]];
                ushort4 v = *(const ushort4*)(vb + (size_t)s * 256 + lane * 4);
                a0 += wgt * busf(v.x); a1 += wgt * busf(v.y);
                a2 += wgt * busf(v.z); a3 += wgt * busf(v.w);
            }
        }
        ushort4 pv;
        pv.x = f2us(a0); pv.y = f2us(a1); pv.z = f2us(a2); pv.w = f2us(a3);
        *(ushort4*)&qsraw[i2][lane * 4] = pv;
    }
    __syncthreads();
    // phase C: tacc[dst][w*64+e] += sum_d MTm[r,w][e][d] * sraw[dst][w*64+d]
    {
        long mtbase = (long)(r * HN + w) * 4096;
        #pragma unroll
        for (int grp = 0; grp < 2; ++grp) {
            int li = grp * 16 + ln;
            bf16x8 B0 = *(const bf16x8*)&qsraw[li][w * 64 + quad * 8];
            bf16x8 B1 = *(const bf16x8*)&qsraw[li][w * 64 + quad * 8 + 32];
            bool store = (li < nd) && (sb_[li + 1] > sb_[li]);
            #pragma unroll
            for (int mt = 0; mt < 4; ++mt) {
                const u16* mp = MTm + mtbase + (mt * 16 + ln) * 64 + quad * 8;
                bf16x8 A0 = *(const bf16x8*)(mp);
                bf16x8 A1 = *(const bf16x8*)(mp + 32);
                f32x4 acc = {0.f, 0.f, 0.f, 0.f};
                acc = __builtin_amdgcn_mfma_f32_16x16x32_bf16(A0, B0, acc, 0, 0, 0);
                acc = __builtin_amdgcn_mfma_f32_16x16x32_bf16(A1, B1, acc, 0, 0, 0);
                if (store) {
                    int jc = w * 64 + mt * 16 + quad * 4;
                    float* tp = tacc + (long)(c0 + li) * 256 + jc;
                    atomicAdd(tp + 0, acc[0]);
                    atomicAdd(tp + 1, acc[1]);
                    atomicAdd(tp + 2, acc[2]);
                    atomicAdd(tp + 3, acc[3]);
                }
            }
        }
    }
}

// ---------------- fused out-linear (MFMA) + skip-gate + LayerNorm ----------------
__global__ __launch_bounds__(512, 4) void k5_fused(const void* __restrict__ x,
        const float* __restrict__ tacc, const u16* __restrict__ WaT,
        const void* __restrict__ ba, const void* __restrict__ skip,
        const void* __restrict__ ln_g, const void* __restrict__ ln_b,
        const int* __restrict__ base,
        const int* __restrict__ lists, const int* __restrict__ cnts,
        const int* __restrict__ flag, void* out) {
    int f = *flag;
    int tt = blockIdx.x % TN, tile = blockIdx.x / TN;
    int cnt = cnts[tt];
    int start = tile * 64;
    if (start >= cnt) return;
    __shared__ int nl[64];
    __shared__ float invs[64];
    __shared__ int hasv[64];
    __shared__ __align__(16) u16 xs[64][280];
    __shared__ __align__(16) float ba_s[256], lnG_s[256], lnB_s[256];
    __shared__ float red1[64][8], red2[64][8];
    __shared__ float mu_[64], rs_[64];
    int t = threadIdx.x;
    if (t < 64) {
        int node = (start + t < cnt) ? lists[tt * NN + start + t] : -1;
        nl[t] = node;
        int nrel = 0;
        if (node >= 0) {
            #pragma unroll
            for (int r = 0; r < RN; ++r)
                nrel += (base[r * NN + node + 1] > base[r * NN + node]) ? 1 : 0;
        }
        hasv[t] = nrel;
        invs[t] = (nrel > 0) ? 1.f / (float)nrel : 1.f;
    }
    if (t < 256) {
        ba_s[t]  = ld(ba,   tt * 256 + t, f);
        lnG_s[t] = ld(ln_g, tt * 256 + t, f);
        lnB_s[t] = ld(ln_b, tt * 256 + t, f);
    }
    __syncthreads();
    // gather tacc (f32) -> xs (bf16, pre-divided by nrel), vectorized
    {
        int i = t >> 3, g8 = t & 7;
        int node = nl[i];
        float inv = invs[i];
        int o0 = g8 * 32;
        u16 tmp[32];
        if (node >= 0) {
            const float* src = tacc + (long)node * 256 + o0;
            #pragma unroll
            for (int j = 0; j < 8; ++j) {
                float4 v = *(const float4*)(src + j * 4);
                tmp[j*4+0] = f2us(v.x * inv); tmp[j*4+1] = f2us(v.y * inv);
                tmp[j*4+2] = f2us(v.z * inv); tmp[j*4+3] = f2us(v.w * inv);
            }
        } else {
            #pragma unroll
            for (int j = 0; j < 32; ++j) tmp[j] = 0;
        }
        #pragma unroll
        for (int j = 0; j < 4; ++j)
            *(uint4*)&xs[i][o0 + j * 8] = ((const uint4*)tmp)[j];
    }
    __syncthreads();
    int w = t >> 6, lane = t & 63, ln = lane & 15, quad = lane >> 4;
    const u16* Wt = WaT + (size_t)tt * 65536;
    f32x4 acc[2][4];
    #pragma unroll
    for (int j = 0; j < 2; ++j)
        #pragma unroll
        for (int g = 0; g < 4; ++g)
            acc[j][g] = (f32x4){0.f, 0.f, 0.f, 0.f};
    for (int kt = 0; kt < 8; ++kt) {
        bf16x8 A[2];
        #pragma unroll
        for (int jt = 0; jt < 2; ++jt)
            A[jt] = *(const bf16x8*)(Wt + (size_t)(w * 32 + jt * 16 + ln) * 256 + kt * 32 + quad * 8);
        bf16x8 B[4];
        #pragma unroll
        for (int g = 0; g < 4; ++g)
            B[g] = *(const bf16x8*)&xs[g * 16 + ln][kt * 32 + quad * 8];
        #pragma unroll
        for (int jt = 0; jt < 2; ++jt)
            #pragma unroll
            for (int g = 0; g < 4; ++g)
                acc[jt][g] = __builtin_amdgcn_mfma_f32_16x16x32_bf16(A[jt], B[g], acc[jt][g], 0, 0, 0);
    }
    float sk = ld(skip, tt, f);
    float alpha = 1.f / (1.f + expf(-sk));
    float p1[4] = {0.f, 0.f, 0.f, 0.f}, p2[4] = {0.f, 0.f, 0.f, 0.f};
    #pragma unroll
    for (int g = 0; g < 4; ++g) {
        int node = nl[g * 16 + ln];
        if (node < 0) continue;
        #pragma unroll
        for (int jt = 0; jt < 2; ++jt) {
            int jc = w * 32 + jt * 16 + quad * 4;
            float4 bi = *(const float4*)&ba_s[jc];
            long xo = (long)node * 256 + jc;
            float xv[4];
            if (f) {
                float4 v = *(const float4*)((const float*)x + xo);
                xv[0] = v.x; xv[1] = v.y; xv[2] = v.z; xv[3] = v.w;
            } else {
                ushort4 v = *(const ushort4*)((const u16*)x + xo);
                xv[0] = busf(v.x); xv[1] = busf(v.y); xv[2] = busf(v.z); xv[3] = busf(v.w);
            }
            #pragma unroll
            for (int rg = 0; rg < 4; ++rg) {
                float ov = acc[jt][g][rg] + ((const float*)&bi)[rg];
                ov = ov * alpha + xv[rg] * (1.f - alpha);
                acc[jt][g][rg] = ov;
                p1[g] += ov; p2[g] += ov * ov;
            }
        }
    }
    #pragma unroll
    for (int g = 0; g < 4; ++g) {
        p1[g] += __shfl_xor(p1[g], 16); p1[g] += __shfl_xor(p1[g], 32);
        p2[g] += __shfl_xor(p2[g], 16); p2[g] += __shfl_xor(p2[g], 32);
    }
    if (quad == 0) {
        #pragma unroll
        for (int g = 0; g < 4; ++g) {
            red1[g * 16 + ln][w] = p1[g];
            red2[g * 16 + ln][w] = p2[g];
        }
    }
    __syncthreads();
    if (t < 64) {
        float s1 = 0.f, s2 = 0.f;
        #pragma unroll
        for (int j = 0; j < 8; ++j) { s1 += red1[t][j]; s2 += red2[t][j]; }
        float mu = s1 * (1.f / 256.f);
        float ms = s2 * (1.f / 256.f);
        float var = fmaxf(ms - mu * mu, 0.f);
        mu_[t] = mu; rs_[t] = rsqrtf(var + 1e-5f);
    }
    __syncthreads();
    #pragma unroll
    for (int g = 0; g < 4; ++g) {
        int li = g * 16 + ln;
        int node = nl[li];
        if (node < 0) continue;
        if (hasv[li] > 0) {
            float mu = mu_[li], rs = rs_[li];
            #pragma unroll
            for (int jt = 0; jt < 2; ++jt) {
                int jc = w * 32 + jt * 16 + quad * 4;
                float4 gg = *(const float4*)&lnG_s[jc];
                float4 bb = *(const float4*)&lnB_s[jc];
                long oo = (long)node * 256 + jc;
                float r0 = (acc[jt][g][0] - mu) * rs * gg.x + bb.x;
                float r1 = (acc[jt][g][1] - mu) * rs * gg.y + bb.y;
                float r2 = (acc[jt][g][2] - mu) * rs * gg.z + bb.z;
                float r3 = (acc[jt][g][3] - mu) * rs * gg.w + bb.w;
                if (f) { float4 v = {r0, r1, r2, r3}; *(float4*)((float*)out + oo) = v; }
                else   { ushort4 v; v.x = f2us(r0); v.y = f2us(r1); v.z = f2us(r2); v.w = f2us(r3);
                         *(ushort4*)((u16*)out + oo) = v; }
            }
        } else {
            #pragma unroll
            for (int jt = 0; jt < 2; ++jt) {
                int jc = w * 32 + jt * 16 + quad * 4;
                long oo = (long)node * 256 + jc;
                if (f) { *(float4*)((float*)out + oo) = *(const float4*)((const float*)x + oo); }
                else   { *(ushort4*)((u16*)out + oo) = *(const ushort4*)((const u16*)x + oo); }
            }
        }
    }
}

extern "C" void kernel_launch(void* const* d_in, const int* in_sizes, int n_in,
                              void* d_out, int out_size, void* d_ws, size_t ws_size,
                              hipStream_t stream) {
    const void* x       = d_in[0];
    const void* Wk      = d_in[1];
    const void* bk      = d_in[2];
    const void* Wq      = d_in[3];
    const void* bq      = d_in[4];
    const void* Wv      = d_in[5];
    const void* bv      = d_in[6];
    const void* Wa      = d_in[7];
    const void* ba      = d_in[8];
    const void* rel_pri = d_in[9];
    const void* rel_att = d_in[10];
    const void* rel_msg = d_in[11];
    const void* skip    = d_in[12];
    const void* ln_g    = d_in[13];
    const void* ln_b    = d_in[14];
    const int* node_type = (const int*)d_in[15];
    const int* edge_src  = (const int*)d_in[16];
    const int* edge_dst  = (const int*)d_in[17];
    const int* edge_type = (const int*)d_in[18];
    char* w = (char*)d_ws;

    // layout (bytes) — total 137,767,552 <= proven ws floor 141,000,128
    u16*      kb     = (u16*)(w);                    // 25,600,000
    u16*      qb     = (u16*)(w + 25600000);         // 25,600,000
    u16*      vb     = (u16*)(w + 51200000);         // 25,600,000
    float*    tacc   = (float*)(w + 76800000);       // 51,200,000 (f32; xb overlay first)
    u16*      xb     = (u16*)(w + 76800000);         //   overlay (consumed by k1)
    u16*      attex  = (u16*)(w + 128000000);        //  3,200,000
    int*      sorted = (int*)(w + 131200000);        //  1,600,000
    int*      base   = (int*)(w + 132800000);        //  1,200,064
    int*      nlists = (int*)(w + 134000064);        //    600,000
    u16*      MTa    = (u16*)(w + 134600064);        //    196,608
    u16*      MTm    = (u16*)(w + 134796672);        //    196,608
    u16*      WallT  = (u16*)(w + 134993280);        //  1,179,648
    u16*      WaT    = (u16*)(w + 136172928);        //    393,216
    // zero region:
    unsigned* cnt    = (unsigned*)(w + 136566144);   //  1,200,000
    int*      ncnts  = (int*)(w + 137766144);        //         64
    int*      flag   = (int*)(w + 137766208);        //         64
    unsigned* csums  = (unsigned*)(w + 137766272);   //      1,280

    hipMemsetAsync(w + 136566144, 0, 1201408, stream);

    detect_dtype<<<dim3(1), dim3(256), 0, stream>>>(x, flag);
    prep<<<dim3(17379), dim3(256), 0, stream>>>(
        rel_att, rel_msg, Wk, Wq, Wv, Wa, x, node_type, edge_dst, edge_type,
        flag, MTa, MTm, WallT, WaT, xb, nlists, ncnts, cnt);
    scanA<<<dim3(NCHUNK), dim3(256), 0, stream>>>(cnt, csums);
    scanB<<<dim3(1), dim3(256), 0, stream>>>(csums, base);
    scanC<<<dim3(NCHUNK), dim3(256), 0, stream>>>(cnt, csums, base);
    scatter_edges<<<dim3((EE + 255) / 256), dim3(256), 0, stream>>>(
        edge_dst, edge_type, base, cnt, sorted);

    k1_mfma<<<dim3(TN * ((NN + 63) / 64)), dim3(512), 0, stream>>>(
        xb, WallT, bk, bq, bv, nlists, ncnts, flag, kb, qb, vb);

    // xb dead after k1 -> zero tacc (f32 accumulator) in its place
    hipMemsetAsync(w + 76800000, 0, 51200000, stream);

    k2k4<<<dim3((NN + CD - 1) / CD, RN), dim3(256), 0, stream>>>(
        kb, qb, vb, MTa, MTm, rel_pri, sorted, base, edge_src, edge_dst,
        flag, attex, tacc);

    k5_fused<<<dim3(TN * ((NN + 63) / 64)), dim3(512), 0, stream>>>(
        x, tacc, WaT, ba, skip, ln_g, ln_b, base, nlists, ncnts, flag, d_out);
}

// Round 7
// 621.892 us; speedup vs baseline: 1.6909x; 1.6909x over previous
//
#include <hip/hip_runtime.h>
#include <hip/hip_bf16.h>

// HGT layer: N=50000, E=400000, D=256, T=3, R=6, H=4, DK=64.
// Round 12: k2k4 r-loop moved INSIDE the block (32 dsts x all 6 relations).
// R11 lesson: 77M f32 atomicAdds -> 883MB WRITE / 1.22GB HBM traffic (724us).
// Now: per-relation MTm fragments accumulate in registers (accF[2][4], +32
// VGPR); ONE float4 tacc store per dst at the end. No atomics, no tacc
// memset, q rows staged once per block. qL is persistent; qrs buffer holds
// qrel then sraw (disjoint phases, synced).

#define NN 50000
#define EE 400000
#define TN 3
#define RN 6
#define HN 4
#define SS (NN * RN)
#define NCHUNK 293   // ceil(SS/1024)
#define CD 32        // dsts per k2k4 block

typedef __hip_bfloat16 bf16;
typedef unsigned short u16;
using bf16x8 = __attribute__((ext_vector_type(8))) __bf16;
using f32x4  = __attribute__((ext_vector_type(4))) float;

__device__ __forceinline__ float b2f(bf16 h) { return __bfloat162float(h); }
__device__ __forceinline__ float busf(u16 u) { return __uint_as_float((unsigned)u << 16); }
__device__ __forceinline__ float blo(unsigned u) { return __uint_as_float(u << 16); }
__device__ __forceinline__ float bhi(unsigned u) { return __uint_as_float(u & 0xffff0000u); }
__device__ __forceinline__ u16 f2us(float f) {   // f32 -> bf16 bits, RNE
    unsigned u = __float_as_uint(f);
    return (u16)((u + 0x7fffu + ((u >> 16) & 1u)) >> 16);
}
__device__ __forceinline__ float ld(const void* p, long i, int f) {
    return f ? ((const float*)p)[i] : b2f(((const bf16*)p)[i]);
}

// ---------------- input dtype sniffer (f32 vs bf16 buffers) ----------------
__global__ __launch_bounds__(256) void detect_dtype(const void* __restrict__ x,
                                                    int* __restrict__ flag) {
    __shared__ int cnt_s;
    if (threadIdx.x == 0) cnt_s = 0;
    __syncthreads();
    const u16* p = (const u16*)x;
    int c = 0;
    for (int i = threadIdx.x; i < 8192; i += 256) {
        int expo = (p[i] >> 7) & 0xFF;
        if (expo >= 0x97) ++c;
    }
    atomicAdd(&cnt_s, c);
    __syncthreads();
    if (threadIdx.x == 0) *flag = (cnt_s > 64) ? 1 : 0;
}

// ---------------- merged prep: transM + transW + convertX + bucket + count ----------------
__global__ __launch_bounds__(256) void prep(const void* __restrict__ rel_att,
        const void* __restrict__ rel_msg,
        const void* __restrict__ Wk, const void* __restrict__ Wq,
        const void* __restrict__ Wv, const void* __restrict__ Wa,
        const void* __restrict__ x, const int* __restrict__ node_type,
        const int* __restrict__ edst, const int* __restrict__ etype,
        const int* __restrict__ flag,
        u16* __restrict__ MTa, u16* __restrict__ MTm,
        u16* __restrict__ WallT, u16* __restrict__ WaT,
        u16* __restrict__ xb,
        int* __restrict__ lists, int* __restrict__ cnts,
        unsigned* __restrict__ cnt) {
    int b = blockIdx.x;
    int t = threadIdx.x;
    if (b < 48) {
        int f = *flag;
        int m = b;                 // 0..23 att copy, 24..47 msg transpose
        long base = (long)(m % 24) * 4096;
        if (m < 24) {
            for (int it = 0; it < 16; ++it) {
                int idx = it * 256 + t;
                MTa[base + idx] = f2us(ld(rel_att, base + idx, f));
            }
        } else {
            for (int it = 0; it < 16; ++it) {
                int idx = it * 256 + t;
                int d = idx >> 6, j = idx & 63;
                MTm[base + (j << 6) + d] = f2us(ld(rel_msg, base + idx, f));
            }
        }
    } else if (b < 3120) {
        int f = *flag;
        int m = b - 48;            // 0..2303 WallT rows, 2304..3071 WaT rows
        if (m < 2304) {
            int ty = m / 768, o3 = m % 768;
            int sec = o3 >> 8, o = o3 & 255;
            const void* W = (sec == 0) ? Wk : (sec == 1) ? Wq : Wv;
            WallT[(size_t)ty * 768 * 256 + (size_t)o3 * 256 + t] =
                f2us(ld(W, (long)ty * 65536 + (long)t * 256 + o, f));
        } else {
            int mm = m - 2304;
            int ty = mm / 256, o = mm % 256;
            WaT[(size_t)ty * 65536 + (size_t)o * 256 + t] =
                f2us(ld(Wa, (long)ty * 65536 + (long)t * 256 + o, f));
        }
    } else if (b < 15620) {
        int f = *flag;
        long i = ((long)(b - 3120) * 256 + t) * 4;
        if (i < (long)NN * 256) {
            if (f) {
                float4 v = *(const float4*)((const float*)x + i);
                ushort4 p; p.x = f2us(v.x); p.y = f2us(v.y); p.z = f2us(v.z); p.w = f2us(v.w);
                *(ushort4*)(xb + i) = p;
            } else {
                *(ushort4*)(xb + i) = *(const ushort4*)((const u16*)x + i);
            }
        }
    } else if (b < 15816) {
        __shared__ int lc[TN], lbase[TN];
        if (t < TN) lc[t] = 0;
        __syncthreads();
        int n = (b - 15620) * 256 + t;
        int pos = -1, ty = 0;
        if (n < NN) {
            ty = node_type[n];
            pos = atomicAdd(&lc[ty], 1);
        }
        __syncthreads();
        if (t < TN) lbase[t] = atomicAdd(&cnts[t], lc[t]);
        __syncthreads();
        if (n < NN) lists[ty * NN + lbase[ty] + pos] = n;
    } else {
        int e = (b - 15816) * 256 + t;
        if (e < EE) atomicAdd(&cnt[etype[e] * NN + edst[e]], 1u);
    }
}

// ---------------- 3-phase exclusive scan over SS segments ----------------
__global__ __launch_bounds__(256) void scanA(const unsigned* __restrict__ cnt,
                                             unsigned* __restrict__ csums) {
    __shared__ unsigned s[256];
    int b = blockIdx.x, t = threadIdx.x;
    int s0 = b * 1024 + t * 4;
    unsigned v = 0;
    if (s0 + 3 < SS) { uint4 u = *(const uint4*)&cnt[s0]; v = u.x + u.y + u.z + u.w; }
    else { for (int j = 0; j < 4; ++j) if (s0 + j < SS) v += cnt[s0 + j]; }
    s[t] = v;
    __syncthreads();
    for (int st = 128; st > 0; st >>= 1) {
        if (t < st) s[t] += s[t + st];
        __syncthreads();
    }
    if (t == 0) csums[b] = s[0];
}

__global__ __launch_bounds__(256) void scanB(unsigned* __restrict__ csums,
                                             int* __restrict__ base) {
    __shared__ unsigned s[512];
    int t = threadIdx.x;
    unsigned a = (t < NCHUNK) ? csums[t] : 0u;
    unsigned b = (256 + t < NCHUNK) ? csums[256 + t] : 0u;
    s[t] = a; s[256 + t] = b;
    __syncthreads();
    for (int st = 1; st < 512; st <<= 1) {
        unsigned x0 = (t >= st) ? s[t - st] : 0u;
        unsigned x1 = (256 + t >= st) ? s[256 + t - st] : 0u;
        __syncthreads();
        s[t] += x0; s[256 + t] += x1;
        __syncthreads();
    }
    if (t < NCHUNK) csums[t] = s[t] - a;
    if (256 + t < NCHUNK) csums[256 + t] = s[256 + t] - b;
    if (t == 0) base[SS] = (int)s[NCHUNK - 1];
}

__global__ __launch_bounds__(256) void scanC(const unsigned* __restrict__ cnt,
        const unsigned* __restrict__ csums, int* __restrict__ base) {
    __shared__ unsigned s[256];
    int b = blockIdx.x, t = threadIdx.x;
    int s0 = b * 1024 + t * 4;
    unsigned vs[4] = {0u, 0u, 0u, 0u};
    if (s0 + 3 < SS) { uint4 u = *(const uint4*)&cnt[s0]; vs[0]=u.x; vs[1]=u.y; vs[2]=u.z; vs[3]=u.w; }
    else { for (int j = 0; j < 4; ++j) if (s0 + j < SS) vs[j] = cnt[s0 + j]; }
    unsigned v = vs[0] + vs[1] + vs[2] + vs[3];
    s[t] = v;
    __syncthreads();
    for (int st = 1; st < 256; st <<= 1) {
        unsigned x = (t >= st) ? s[t - st] : 0u;
        __syncthreads();
        s[t] += x;
        __syncthreads();
    }
    unsigned run = csums[b] + s[t] - v;
    for (int j = 0; j < 4; ++j) {
        if (s0 + j < SS) { base[s0 + j] = (int)run; run += vs[j]; }
    }
}

// ---------------- scatter edges into seg-sorted order (consumes cnt) ----------------
__global__ __launch_bounds__(256) void scatter_edges(const int* __restrict__ edst,
        const int* __restrict__ etype, const int* __restrict__ base,
        unsigned* __restrict__ cnt, int* __restrict__ sorted) {
    int e = blockIdx.x * 256 + threadIdx.x;
    if (e >= EE) return;
    int seg = etype[e] * NN + edst[e];
    unsigned old = atomicSub(&cnt[seg], 1u);
    sorted[base[seg] + (int)old - 1] = e;
}

// ---------------- k/q/v typed linear via MFMA (64 same-type nodes / block) ----------------
__global__ __launch_bounds__(512, 2) void k1_mfma(const u16* __restrict__ xb,
        const u16* __restrict__ WallT,
        const void* __restrict__ bk, const void* __restrict__ bq,
        const void* __restrict__ bv,
        const int* __restrict__ lists, const int* __restrict__ cnts,
        const int* __restrict__ flag,
        u16* __restrict__ kb, u16* __restrict__ qb, u16* __restrict__ vb) {
    int f = *flag;
    int tt = blockIdx.x % TN, tile = blockIdx.x / TN;
    int cnt = cnts[tt];
    int start = tile * 64;
    if (start >= cnt) return;
    __shared__ int nl[64];
    __shared__ __align__(16) u16 xs[64][280];
    __shared__ __align__(16) float bias_s[768];
    int t = threadIdx.x;
    if (t < 64) nl[t] = (start + t < cnt) ? lists[tt * NN + start + t] : -1;
    if (t < 256) {
        bias_s[t]       = ld(bk, tt * 256 + t, f);
        bias_s[256 + t] = ld(bq, tt * 256 + t, f);
        bias_s[512 + t] = ld(bv, tt * 256 + t, f);
    }
    __syncthreads();
    {
        int i = t >> 4, g = t & 15;
        #pragma unroll
        for (int i2 = 0; i2 < 2; ++i2) {
            int row = i + i2 * 32;
            int node = nl[row];
            uint4 a = {0, 0, 0, 0}, b = {0, 0, 0, 0};
            if (node >= 0) {
                const uint4* src = (const uint4*)(xb + (size_t)node * 256 + g * 16);
                a = src[0]; b = src[1];
            }
            *(uint4*)&xs[row][g * 16] = a;
            *(uint4*)&xs[row][g * 16 + 8] = b;
        }
    }
    __syncthreads();
    int w = t >> 6, lane = t & 63, ln = lane & 15, quad = lane >> 4;
    const u16* Wt = WallT + (size_t)tt * 768 * 256;
    f32x4 acc[6][4];
    #pragma unroll
    for (int j = 0; j < 6; ++j)
        #pragma unroll
        for (int g = 0; g < 4; ++g)
            acc[j][g] = (f32x4){0.f, 0.f, 0.f, 0.f};
    for (int kt = 0; kt < 8; ++kt) {
        bf16x8 A[6];
        #pragma unroll
        for (int jt = 0; jt < 6; ++jt)
            A[jt] = *(const bf16x8*)(Wt + (size_t)(w * 96 + jt * 16 + ln) * 256 + kt * 32 + quad * 8);
        bf16x8 B[4];
        #pragma unroll
        for (int g = 0; g < 4; ++g)
            B[g] = *(const bf16x8*)&xs[g * 16 + ln][kt * 32 + quad * 8];
        #pragma unroll
        for (int jt = 0; jt < 6; ++jt)
            #pragma unroll
            for (int g = 0; g < 4; ++g)
                acc[jt][g] = __builtin_amdgcn_mfma_f32_16x16x32_bf16(A[jt], B[g], acc[jt][g], 0, 0, 0);
    }
    #pragma unroll
    for (int jt = 0; jt < 6; ++jt) {
        int jc = w * 96 + jt * 16 + quad * 4;
        float4 bi = *(const float4*)&bias_s[jc];
        int sec = jc >> 8, o = jc & 255;
        u16* basep = (sec == 0 ? kb : sec == 1 ? qb : vb);
        #pragma unroll
        for (int g = 0; g < 4; ++g) {
            int node = nl[g * 16 + ln];
            if (node >= 0) {
                ushort4 p;
                p.x = f2us(acc[jt][g][0] + bi.x); p.y = f2us(acc[jt][g][1] + bi.y);
                p.z = f2us(acc[jt][g][2] + bi.z); p.w = f2us(acc[jt][g][3] + bi.w);
                *(ushort4*)(basep + (size_t)node * 256 + o) = p;
            }
        }
    }
}

// ---------------- fused attention + aggregation, r-loop in block ----------------
// grid ceil(NN/CD); block = CD consecutive dsts, loops r=0..5.
// qL: staged q rows (persistent). qrs: qrel (ph0.5-A) then sraw (phB-C).
// Per r: qrel=MTa@q -> logits/denom -> raw vb sums -> accF += MTm@sraw.
// Final: one float4 store per (dst, dim-block) to tacc. No atomics.
__global__ __launch_bounds__(256) void k2k4(const u16* __restrict__ kb,
        const u16* __restrict__ qb, const u16* __restrict__ vb,
        const u16* __restrict__ MTa, const u16* __restrict__ MTm,
        const void* __restrict__ rel_pri,
        const int* __restrict__ sorted, const int* __restrict__ base,
        const int* __restrict__ esrc, const int* __restrict__ edst,
        const int* __restrict__ flag,
        u16* __restrict__ attex_g, float* __restrict__ tacc) {
    int f = *flag;
    int c0 = blockIdx.x * CD;
    int nd = min(CD, NN - c0);
    __shared__ float attL[1280];
    __shared__ int srcL[1280];
    __shared__ float denomL[CD * HN];
    __shared__ int sb_[CD + 1];
    __shared__ __align__(16) u16 qL[CD][264];
    __shared__ __align__(16) u16 qrs[CD][264];
    int t = threadIdx.x;
    int w = t >> 6, lane = t & 63, ln = lane & 15, quad = lane >> 4;
    // stage q rows ONCE
    {
        int i = t >> 3, g8 = t & 7;
        uint4 a0 = {0,0,0,0}, a1 = {0,0,0,0}, a2 = {0,0,0,0}, a3 = {0,0,0,0};
        if (i < nd) {
            const uint4* src = (const uint4*)(qb + (size_t)(c0 + i) * 256 + g8 * 32);
            a0 = src[0]; a1 = src[1]; a2 = src[2]; a3 = src[3];
        }
        *(uint4*)&qL[i][g8 * 32 +  0] = a0;
        *(uint4*)&qL[i][g8 * 32 +  8] = a1;
        *(uint4*)&qL[i][g8 * 32 + 16] = a2;
        *(uint4*)&qL[i][g8 * 32 + 24] = a3;
    }
    f32x4 accF[2][4];
    #pragma unroll
    for (int g = 0; g < 2; ++g)
        #pragma unroll
        for (int m = 0; m < 4; ++m)
            accF[g][m] = (f32x4){0.f, 0.f, 0.f, 0.f};

    for (int r = 0; r < RN; ++r) {
        if (t < CD * HN) denomL[t] = 0.f;
        if (t <= nd) sb_[t] = base[r * NN + c0 + t];
        __syncthreads();   // S1: sb/denom ready; prev phase C done with qrs; qL ready (r=0)
        long mtbase = (long)(r * HN + w) * 4096;
        // phase 0.5: qrs := qrel = MTa[r] @ qL   (wave = head)
        #pragma unroll
        for (int grp = 0; grp < 2; ++grp) {
            int li = grp * 16 + ln;
            bf16x8 B0 = *(const bf16x8*)&qL[li][w * 64 + quad * 8];
            bf16x8 B1 = *(const bf16x8*)&qL[li][w * 64 + quad * 8 + 32];
            #pragma unroll
            for (int mt = 0; mt < 4; ++mt) {
                const u16* ap = MTa + mtbase + (mt * 16 + ln) * 64 + quad * 8;
                bf16x8 A0 = *(const bf16x8*)(ap);
                bf16x8 A1 = *(const bf16x8*)(ap + 32);
                f32x4 acc = {0.f, 0.f, 0.f, 0.f};
                acc = __builtin_amdgcn_mfma_f32_16x16x32_bf16(A0, B0, acc, 0, 0, 0);
                acc = __builtin_amdgcn_mfma_f32_16x16x32_bf16(A1, B1, acc, 0, 0, 0);
                int jc = w * 64 + mt * 16 + quad * 4;
                ushort4 pq;
                pq.x = f2us(acc[0]); pq.y = f2us(acc[1]);
                pq.z = f2us(acc[2]); pq.w = f2us(acc[3]);
                *(ushort4*)&qrs[li][jc] = pq;
            }
        }
        __syncthreads();   // S2: qrel ready
        int b0 = sb_[0], nE = sb_[nd] - b0;
        // phase A: att logits -> exp (thread per edge-head)
        for (int i = t; i < nE * 4; i += 256) {
            int ei = i >> 2;
            int e = sorted[b0 + ei];
            int h = i & 3;
            int s = esrc[e], dv = edst[e] - c0;
            if (h == 0 && ei < 1280) srcL[ei] = s;
            const uint4* kp = (const uint4*)(kb + (size_t)s * 256 + h * 64);
            const uint4* qp = (const uint4*)&qrs[dv][h * 64];
            float dot = 0.f;
            #pragma unroll
            for (int ii = 0; ii < 8; ++ii) {
                uint4 a = kp[ii], b = qp[ii];
                dot += blo(a.x) * blo(b.x) + bhi(a.x) * bhi(b.x);
                dot += blo(a.y) * blo(b.y) + bhi(a.y) * bhi(b.y);
                dot += blo(a.z) * blo(b.z) + bhi(a.z) * bhi(b.z);
                dot += blo(a.w) * blo(b.w) + bhi(a.w) * bhi(b.w);
            }
            float attv = dot * ld(rel_pri, r * HN + h, f) * 0.125f;
            attv = fminf(fmaxf(attv, -50.f), 50.f);
            float ex = expf(attv);
            if (i < 1280) attL[i] = ex;
            else attex_g[(size_t)b0 * 4 + i] = f2us(ex);   // statistical never-path
            atomicAdd(&denomL[dv * HN + h], ex);
        }
        __syncthreads();   // S3: denom ready, qrel dead
        // phase B: qrs := sraw = normalized weighted vb sums (wave per dst)
        for (int i2 = w; i2 < nd; i2 += 4) {
            int sb = sb_[i2], se = sb_[i2 + 1];
            float a0 = 0.f, a1 = 0.f, a2 = 0.f, a3 = 0.f;
            if (se > sb) {
                int h = lane >> 4;
                float inv = 1.f / denomL[i2 * HN + h];
                for (int idx = sb; idx < se; ++idx) {
                    int rel = idx - b0;
                    int li2 = rel * 4 + h;
                    float wgt = ((li2 < 1280) ? attL[li2] : busf(attex_g[(size_t)idx * 4 + h])) * inv;
                    int s = (rel < 1280) ? srcL[rel] : esrc[sorted[idx]];
                    ushort4 v = *(const ushort4*)(vb + (size_t)s * 256 + lane * 4);
                    a0 += wgt * busf(v.x); a1 += wgt * busf(v.y);
                    a2 += wgt * busf(v.z); a3 += wgt * busf(v.w);
                }
            }
            ushort4 pv;
            pv.x = f2us(a0); pv.y = f2us(a1); pv.z = f2us(a2); pv.w = f2us(a3);
            *(ushort4*)&qrs[i2][lane * 4] = pv;
        }
        __syncthreads();   // S4: sraw ready
        // phase C: accF += MTm[r] @ sraw  (register accumulation; empty segs add 0)
        #pragma unroll
        for (int grp = 0; grp < 2; ++grp) {
            int li = grp * 16 + ln;
            bf16x8 B0 = *(const bf16x8*)&qrs[li][w * 64 + quad * 8];
            bf16x8 B1 = *(const bf16x8*)&qrs[li][w * 64 + quad * 8 + 32];
            #pragma unroll
            for (int mt = 0; mt < 4; ++mt) {
                const u16* mp = MTm + mtbase + (mt * 16 + ln) * 64 + quad * 8;
                bf16x8 A0 = *(const bf16x8*)(mp);
                bf16x8 A1 = *(const bf16x8*)(mp + 32);
                accF[grp][mt] = __builtin_amdgcn_mfma_f32_16x16x32_bf16(A0, B0, accF[grp][mt], 0, 0, 0);
                accF[grp][mt] = __builtin_amdgcn_mfma_f32_16x16x32_bf16(A1, B1, accF[grp][mt], 0, 0, 0);
            }
        }
        // next iteration's S1 separates phase C reads from next phase 0.5 writes
    }
    // single tacc write (f32, no atomics)
    #pragma unroll
    for (int grp = 0; grp < 2; ++grp) {
        int li = grp * 16 + ln;
        if (li < nd) {
            #pragma unroll
            for (int mt = 0; mt < 4; ++mt) {
                int jc = w * 64 + mt * 16 + quad * 4;
                float4 v = {accF[grp][mt][0], accF[grp][mt][1],
                            accF[grp][mt][2], accF[grp][mt][3]};
                *(float4*)(tacc + (long)(c0 + li) * 256 + jc) = v;
            }
        }
    }
}

// ---------------- fused out-linear (MFMA) + skip-gate + LayerNorm ----------------
__global__ __launch_bounds__(512, 4) void k5_fused(const void* __restrict__ x,
        const float* __restrict__ tacc, const u16* __restrict__ WaT,
        const void* __restrict__ ba, const void* __restrict__ skip,
        const void* __restrict__ ln_g, const void* __restrict__ ln_b,
        const int* __restrict__ base,
        const int* __restrict__ lists, const int* __restrict__ cnts,
        const int* __restrict__ flag, void* out) {
    int f = *flag;
    int tt = blockIdx.x % TN, tile = blockIdx.x / TN;
    int cnt = cnts[tt];
    int start = tile * 64;
    if (start >= cnt) return;
    __shared__ int nl[64];
    __shared__ float invs[64];
    __shared__ int hasv[64];
    __shared__ __align__(16) u16 xs[64][280];
    __shared__ __align__(16) float ba_s[256], lnG_s[256], lnB_s[256];
    __shared__ float red1[64][8], red2[64][8];
    __shared__ float mu_[64], rs_[64];
    int t = threadIdx.x;
    if (t < 64) {
        int node = (start + t < cnt) ? lists[tt * NN + start + t] : -1;
        nl[t] = node;
        int nrel = 0;
        if (node >= 0) {
            #pragma unroll
            for (int r = 0; r < RN; ++r)
                nrel += (base[r * NN + node + 1] > base[r * NN + node]) ? 1 : 0;
        }
        hasv[t] = nrel;
        invs[t] = (nrel > 0) ? 1.f / (float)nrel : 1.f;
    }
    if (t < 256) {
        ba_s[t]  = ld(ba,   tt * 256 + t, f);
        lnG_s[t] = ld(ln_g, tt * 256 + t, f);
        lnB_s[t] = ld(ln_b, tt * 256 + t, f);
    }
    __syncthreads();
    // gather tacc (f32) -> xs (bf16, pre-divided by nrel), vectorized
    {
        int i = t >> 3, g8 = t & 7;
        int node = nl[i];
        float inv = invs[i];
        int o0 = g8 * 32;
        u16 tmp[32];
        if (node >= 0) {
            const float* src = tacc + (long)node * 256 + o0;
            #pragma unroll
            for (int j = 0; j < 8; ++j) {
                float4 v = *(const float4*)(src + j * 4);
                tmp[j*4+0] = f2us(v.x * inv); tmp[j*4+1] = f2us(v.y * inv);
                tmp[j*4+2] = f2us(v.z * inv); tmp[j*4+3] = f2us(v.w * inv);
            }
        } else {
            #pragma unroll
            for (int j = 0; j < 32; ++j) tmp[j] = 0;
        }
        #pragma unroll
        for (int j = 0; j < 4; ++j)
            *(uint4*)&xs[i][o0 + j * 8] = ((const uint4*)tmp)[j];
    }
    __syncthreads();
    int w = t >> 6, lane = t & 63, ln = lane & 15, quad = lane >> 4;
    const u16* Wt = WaT + (size_t)tt * 65536;
    f32x4 acc[2][4];
    #pragma unroll
    for (int j = 0; j < 2; ++j)
        #pragma unroll
        for (int g = 0; g < 4; ++g)
            acc[j][g] = (f32x4){0.f, 0.f, 0.f, 0.f};
    for (int kt = 0; kt < 8; ++kt) {
        bf16x8 A[2];
        #pragma unroll
        for (int jt = 0; jt < 2; ++jt)
            A[jt] = *(const bf16x8*)(Wt + (size_t)(w * 32 + jt * 16 + ln) * 256 + kt * 32 + quad * 8);
        bf16x8 B[4];
        #pragma unroll
        for (int g = 0; g < 4; ++g)
            B[g] = *(const bf16x8*)&xs[g * 16 + ln][kt * 32 + quad * 8];
        #pragma unroll
        for (int jt = 0; jt < 2; ++jt)
            #pragma unroll
            for (int g = 0; g < 4; ++g)
                acc[jt][g] = __builtin_amdgcn_mfma_f32_16x16x32_bf16(A[jt], B[g], acc[jt][g], 0, 0, 0);
    }
    float sk = ld(skip, tt, f);
    float alpha = 1.f / (1.f + expf(-sk));
    float p1[4] = {0.f, 0.f, 0.f, 0.f}, p2[4] = {0.f, 0.f, 0.f, 0.f};
    #pragma unroll
    for (int g = 0; g < 4; ++g) {
        int node = nl[g * 16 + ln];
        if (node < 0) continue;
        #pragma unroll
        for (int jt = 0; jt < 2; ++jt) {
            int jc = w * 32 + jt * 16 + quad * 4;
            float4 bi = *(const float4*)&ba_s[jc];
            long xo = (long)node * 256 + jc;
            float xv[4];
            if (f) {
                float4 v = *(const float4*)((const float*)x + xo);
                xv[0] = v.x; xv[1] = v.y; xv[2] = v.z; xv[3] = v.w;
            } else {
                ushort4 v = *(const ushort4*)((const u16*)x + xo);
                xv[0] = busf(v.x); xv[1] = busf(v.y); xv[2] = busf(v.z); xv[3] = busf(v.w);
            }
            #pragma unroll
            for (int rg = 0; rg < 4; ++rg) {
                float ov = acc[jt][g][rg] + ((const float*)&bi)[rg];
                ov = ov * alpha + xv[rg] * (1.f - alpha);
                acc[jt][g][rg] = ov;
                p1[g] += ov; p2[g] += ov * ov;
            }
        }
    }
    #pragma unroll
    for (int g = 0; g < 4; ++g) {
        p1[g] += __shfl_xor(p1[g], 16); p1[g] += __shfl_xor(p1[g], 32);
        p2[g] += __shfl_xor(p2[g], 16); p2[g] += __shfl_xor(p2[g], 32);
    }
    if (quad == 0) {
        #pragma unroll
        for (int g = 0; g < 4; ++g) {
            red1[g * 16 + ln][w] = p1[g];
            red2[g * 16 + ln][w] = p2[g];
        }
    }
    __syncthreads();
    if (t < 64) {
        float s1 = 0.f, s2 = 0.f;
        #pragma unroll
        for (int j = 0; j < 8; ++j) { s1 += red1[t][j]; s2 += red2[t][j]; }
        float mu = s1 * (1.f / 256.f);
        float ms = s2 * (1.f / 256.f);
        float var = fmaxf(ms - mu * mu, 0.f);
        mu_[t] = mu; rs_[t] = rsqrtf(var + 1e-5f);
    }
    __syncthreads();
    #pragma unroll
    for (int g = 0; g < 4; ++g) {
        int li = g * 16 + ln;
        int node = nl[li];
        if (node < 0) continue;
        if (hasv[li] > 0) {
            float mu = mu_[li], rs = rs_[li];
            #pragma unroll
            for (int jt = 0; jt < 2; ++jt) {
                int jc = w * 32 + jt * 16 + quad * 4;
                float4 gg = *(const float4*)&lnG_s[jc];
                float4 bb = *(const float4*)&lnB_s[jc];
                long oo = (long)node * 256 + jc;
                float r0 = (acc[jt][g][0] - mu) * rs * gg.x + bb.x;
                float r1 = (acc[jt][g][1] - mu) * rs * gg.y + bb.y;
                float r2 = (acc[jt][g][2] - mu) * rs * gg.z + bb.z;
                float r3 = (acc[jt][g][3] - mu) * rs * gg.w + bb.w;
                if (f) { float4 v = {r0, r1, r2, r3}; *(float4*)((float*)out + oo) = v; }
                else   { ushort4 v; v.x = f2us(r0); v.y = f2us(r1); v.z = f2us(r2); v.w = f2us(r3);
                         *(ushort4*)((u16*)out + oo) = v; }
            }
        } else {
            #pragma unroll
            for (int jt = 0; jt < 2; ++jt) {
                int jc = w * 32 + jt * 16 + quad * 4;
                long oo = (long)node * 256 + jc;
                if (f) { *(float4*)((float*)out + oo) = *(const float4*)((const float*)x + oo); }
                else   { *(ushort4*)((u16*)out + oo) = *(const ushort4*)((const u16*)x + oo); }
            }
        }
    }
}

extern "C" void kernel_launch(void* const* d_in, const int* in_sizes, int n_in,
                              void* d_out, int out_size, void* d_ws, size_t ws_size,
                              hipStream_t stream) {
    const void* x       = d_in[0];
    const void* Wk      = d_in[1];
    const void* bk      = d_in[2];
    const void* Wq      = d_in[3];
    const void* bq      = d_in[4];
    const void* Wv      = d_in[5];
    const void* bv      = d_in[6];
    const void* Wa      = d_in[7];
    const void* ba      = d_in[8];
    const void* rel_pri = d_in[9];
    const void* rel_att = d_in[10];
    const void* rel_msg = d_in[11];
    const void* skip    = d_in[12];
    const void* ln_g    = d_in[13];
    const void* ln_b    = d_in[14];
    const int* node_type = (const int*)d_in[15];
    const int* edge_src  = (const int*)d_in[16];
    const int* edge_dst  = (const int*)d_in[17];
    const int* edge_type = (const int*)d_in[18];
    char* w = (char*)d_ws;

    // layout (bytes) — total 137,767,552 <= proven ws floor 141,000,128
    u16*      kb     = (u16*)(w);                    // 25,600,000
    u16*      qb     = (u16*)(w + 25600000);         // 25,600,000
    u16*      vb     = (u16*)(w + 51200000);         // 25,600,000
    float*    tacc   = (float*)(w + 76800000);       // 51,200,000 (f32; xb overlay first)
    u16*      xb     = (u16*)(w + 76800000);         //   overlay (consumed by k1)
    u16*      attex  = (u16*)(w + 128000000);        //  3,200,000
    int*      sorted = (int*)(w + 131200000);        //  1,600,000
    int*      base   = (int*)(w + 132800000);        //  1,200,064
    int*      nlists = (int*)(w + 134000064);        //    600,000
    u16*      MTa    = (u16*)(w + 134600064);        //    196,608
    u16*      MTm    = (u16*)(w + 134796672);        //    196,608
    u16*      WallT  = (u16*)(w + 134993280);        //  1,179,648
    u16*      WaT    = (u16*)(w + 136172928);        //    393,216
    // zero region:
    unsigned* cnt    = (unsigned*)(w + 136566144);   //  1,200,000
    int*      ncnts  = (int*)(w + 137766144);        //         64
    int*      flag   = (int*)(w + 137766208);        //         64
    unsigned* csums  = (unsigned*)(w + 137766272);   //      1,280

    hipMemsetAsync(w + 136566144, 0, 1201408, stream);

    detect_dtype<<<dim3(1), dim3(256), 0, stream>>>(x, flag);
    prep<<<dim3(17379), dim3(256), 0, stream>>>(
        rel_att, rel_msg, Wk, Wq, Wv, Wa, x, node_type, edge_dst, edge_type,
        flag, MTa, MTm, WallT, WaT, xb, nlists, ncnts, cnt);
    scanA<<<dim3(NCHUNK), dim3(256), 0, stream>>>(cnt, csums);
    scanB<<<dim3(1), dim3(256), 0, stream>>>(csums, base);
    scanC<<<dim3(NCHUNK), dim3(256), 0, stream>>>(cnt, csums, base);
    scatter_edges<<<dim3((EE + 255) / 256), dim3(256), 0, stream>>>(
        edge_dst, edge_type, base, cnt, sorted);

    k1_mfma<<<dim3(TN * ((NN + 63) / 64)), dim3(512), 0, stream>>>(
        xb, WallT, bk, bq, bv, nlists, ncnts, flag, kb, qb, vb);

    // tacc fully overwritten by k2k4 (register accumulation) -> no memset

    k2k4<<<dim3((NN + CD - 1) / CD), dim3(256), 0, stream>>>(
        kb, qb, vb, MTa, MTm, rel_pri, sorted, base, edge_src, edge_dst,
        flag, attex, tacc);

    k5_fused<<<dim3(TN * ((NN + 63) / 64)), dim3(512), 0, stream>>>(
        x, tacc, WaT, ba, skip, ln_g, ln_b, base, nlists, ncnts, flag, d_out);
}

// Round 8
// 588.611 us; speedup vs baseline: 1.7865x; 1.0565x over previous
//
#include <hip/hip_runtime.h>
#include <hip/hip_bf16.h>

// HGT layer: N=50000, E=400000, D=256, T=3, R=6, H=4, DK=64.
// Round 13: k2k4 MLP boost. R12 counters: 250MB L2-miss gathers @ ~1TB/s,
// occupancy 18.6% (45KB LDS -> 3 blocks/CU) = latency-bound. Changes:
//  - CD 32 -> 16 (50000 = 3125*16, no partial block): LDS 45 -> ~22.4KB
//    -> 7 blocks/CU (28 waves vs 12).
//  - phase B: wave handles 2 dsts (half-wave each), 16B vb loads per lane.
//  - MFMA phases single-group (accF[4], -16 VGPR).
// Kept: r-loop in block, register accumulation, no atomics (R12 lesson:
// 77M atomicAdds = 883MB writes = 724us).

#define NN 50000
#define EE 400000
#define TN 3
#define RN 6
#define HN 4
#define SS (NN * RN)
#define NCHUNK 293   // ceil(SS/1024)
#define CD 16        // dsts per k2k4 block
#define LCAP 640     // LDS edge cache cap (attL edge-heads, srcL edges)

typedef __hip_bfloat16 bf16;
typedef unsigned short u16;
using bf16x8 = __attribute__((ext_vector_type(8))) __bf16;
using f32x4  = __attribute__((ext_vector_type(4))) float;

__device__ __forceinline__ float b2f(bf16 h) { return __bfloat162float(h); }
__device__ __forceinline__ float busf(u16 u) { return __uint_as_float((unsigned)u << 16); }
__device__ __forceinline__ float blo(unsigned u) { return __uint_as_float(u << 16); }
__device__ __forceinline__ float bhi(unsigned u) { return __uint_as_float(u & 0xffff0000u); }
__device__ __forceinline__ u16 f2us(float f) {   // f32 -> bf16 bits, RNE
    unsigned u = __float_as_uint(f);
    return (u16)((u + 0x7fffu + ((u >> 16) & 1u)) >> 16);
}
__device__ __forceinline__ float ld(const void* p, long i, int f) {
    return f ? ((const float*)p)[i] : b2f(((const bf16*)p)[i]);
}

// ---------------- input dtype sniffer (f32 vs bf16 buffers) ----------------
__global__ __launch_bounds__(256) void detect_dtype(const void* __restrict__ x,
                                                    int* __restrict__ flag) {
    __shared__ int cnt_s;
    if (threadIdx.x == 0) cnt_s = 0;
    __syncthreads();
    const u16* p = (const u16*)x;
    int c = 0;
    for (int i = threadIdx.x; i < 8192; i += 256) {
        int expo = (p[i] >> 7) & 0xFF;
        if (expo >= 0x97) ++c;
    }
    atomicAdd(&cnt_s, c);
    __syncthreads();
    if (threadIdx.x == 0) *flag = (cnt_s > 64) ? 1 : 0;
}

// ---------------- merged prep: transM + transW + convertX + bucket + count ----------------
__global__ __launch_bounds__(256) void prep(const void* __restrict__ rel_att,
        const void* __restrict__ rel_msg,
        const void* __restrict__ Wk, const void* __restrict__ Wq,
        const void* __restrict__ Wv, const void* __restrict__ Wa,
        const void* __restrict__ x, const int* __restrict__ node_type,
        const int* __restrict__ edst, const int* __restrict__ etype,
        const int* __restrict__ flag,
        u16* __restrict__ MTa, u16* __restrict__ MTm,
        u16* __restrict__ WallT, u16* __restrict__ WaT,
        u16* __restrict__ xb,
        int* __restrict__ lists, int* __restrict__ cnts,
        unsigned* __restrict__ cnt) {
    int b = blockIdx.x;
    int t = threadIdx.x;
    if (b < 48) {
        int f = *flag;
        int m = b;                 // 0..23 att copy, 24..47 msg transpose
        long base = (long)(m % 24) * 4096;
        if (m < 24) {
            for (int it = 0; it < 16; ++it) {
                int idx = it * 256 + t;
                MTa[base + idx] = f2us(ld(rel_att, base + idx, f));
            }
        } else {
            for (int it = 0; it < 16; ++it) {
                int idx = it * 256 + t;
                int d = idx >> 6, j = idx & 63;
                MTm[base + (j << 6) + d] = f2us(ld(rel_msg, base + idx, f));
            }
        }
    } else if (b < 3120) {
        int f = *flag;
        int m = b - 48;            // 0..2303 WallT rows, 2304..3071 WaT rows
        if (m < 2304) {
            int ty = m / 768, o3 = m % 768;
            int sec = o3 >> 8, o = o3 & 255;
            const void* W = (sec == 0) ? Wk : (sec == 1) ? Wq : Wv;
            WallT[(size_t)ty * 768 * 256 + (size_t)o3 * 256 + t] =
                f2us(ld(W, (long)ty * 65536 + (long)t * 256 + o, f));
        } else {
            int mm = m - 2304;
            int ty = mm / 256, o = mm % 256;
            WaT[(size_t)ty * 65536 + (size_t)o * 256 + t] =
                f2us(ld(Wa, (long)ty * 65536 + (long)t * 256 + o, f));
        }
    } else if (b < 15620) {
        int f = *flag;
        long i = ((long)(b - 3120) * 256 + t) * 4;
        if (i < (long)NN * 256) {
            if (f) {
                float4 v = *(const float4*)((const float*)x + i);
                ushort4 p; p.x = f2us(v.x); p.y = f2us(v.y); p.z = f2us(v.z); p.w = f2us(v.w);
                *(ushort4*)(xb + i) = p;
            } else {
                *(ushort4*)(xb + i) = *(const ushort4*)((const u16*)x + i);
            }
        }
    } else if (b < 15816) {
        __shared__ int lc[TN], lbase[TN];
        if (t < TN) lc[t] = 0;
        __syncthreads();
        int n = (b - 15620) * 256 + t;
        int pos = -1, ty = 0;
        if (n < NN) {
            ty = node_type[n];
            pos = atomicAdd(&lc[ty], 1);
        }
        __syncthreads();
        if (t < TN) lbase[t] = atomicAdd(&cnts[t], lc[t]);
        __syncthreads();
        if (n < NN) lists[ty * NN + lbase[ty] + pos] = n;
    } else {
        int e = (b - 15816) * 256 + t;
        if (e < EE) atomicAdd(&cnt[etype[e] * NN + edst[e]], 1u);
    }
}

// ---------------- 3-phase exclusive scan over SS segments ----------------
__global__ __launch_bounds__(256) void scanA(const unsigned* __restrict__ cnt,
                                             unsigned* __restrict__ csums) {
    __shared__ unsigned s[256];
    int b = blockIdx.x, t = threadIdx.x;
    int s0 = b * 1024 + t * 4;
    unsigned v = 0;
    if (s0 + 3 < SS) { uint4 u = *(const uint4*)&cnt[s0]; v = u.x + u.y + u.z + u.w; }
    else { for (int j = 0; j < 4; ++j) if (s0 + j < SS) v += cnt[s0 + j]; }
    s[t] = v;
    __syncthreads();
    for (int st = 128; st > 0; st >>= 1) {
        if (t < st) s[t] += s[t + st];
        __syncthreads();
    }
    if (t == 0) csums[b] = s[0];
}

__global__ __launch_bounds__(256) void scanB(unsigned* __restrict__ csums,
                                             int* __restrict__ base) {
    __shared__ unsigned s[512];
    int t = threadIdx.x;
    unsigned a = (t < NCHUNK) ? csums[t] : 0u;
    unsigned b = (256 + t < NCHUNK) ? csums[256 + t] : 0u;
    s[t] = a; s[256 + t] = b;
    __syncthreads();
    for (int st = 1; st < 512; st <<= 1) {
        unsigned x0 = (t >= st) ? s[t - st] : 0u;
        unsigned x1 = (256 + t >= st) ? s[256 + t - st] : 0u;
        __syncthreads();
        s[t] += x0; s[256 + t] += x1;
        __syncthreads();
    }
    if (t < NCHUNK) csums[t] = s[t] - a;
    if (256 + t < NCHUNK) csums[256 + t] = s[256 + t] - b;
    if (t == 0) base[SS] = (int)s[NCHUNK - 1];
}

__global__ __launch_bounds__(256) void scanC(const unsigned* __restrict__ cnt,
        const unsigned* __restrict__ csums, int* __restrict__ base) {
    __shared__ unsigned s[256];
    int b = blockIdx.x, t = threadIdx.x;
    int s0 = b * 1024 + t * 4;
    unsigned vs[4] = {0u, 0u, 0u, 0u};
    if (s0 + 3 < SS) { uint4 u = *(const uint4*)&cnt[s0]; vs[0]=u.x; vs[1]=u.y; vs[2]=u.z; vs[3]=u.w; }
    else { for (int j = 0; j < 4; ++j) if (s0 + j < SS) vs[j] = cnt[s0 + j]; }
    unsigned v = vs[0] + vs[1] + vs[2] + vs[3];
    s[t] = v;
    __syncthreads();
    for (int st = 1; st < 256; st <<= 1) {
        unsigned x = (t >= st) ? s[t - st] : 0u;
        __syncthreads();
        s[t] += x;
        __syncthreads();
    }
    unsigned run = csums[b] + s[t] - v;
    for (int j = 0; j < 4; ++j) {
        if (s0 + j < SS) { base[s0 + j] = (int)run; run += vs[j]; }
    }
}

// ---------------- scatter edges into seg-sorted order (consumes cnt) ----------------
__global__ __launch_bounds__(256) void scatter_edges(const int* __restrict__ edst,
        const int* __restrict__ etype, const int* __restrict__ base,
        unsigned* __restrict__ cnt, int* __restrict__ sorted) {
    int e = blockIdx.x * 256 + threadIdx.x;
    if (e >= EE) return;
    int seg = etype[e] * NN + edst[e];
    unsigned old = atomicSub(&cnt[seg], 1u);
    sorted[base[seg] + (int)old - 1] = e;
}

// ---------------- k/q/v typed linear via MFMA (64 same-type nodes / block) ----------------
__global__ __launch_bounds__(512, 2) void k1_mfma(const u16* __restrict__ xb,
        const u16* __restrict__ WallT,
        const void* __restrict__ bk, const void* __restrict__ bq,
        const void* __restrict__ bv,
        const int* __restrict__ lists, const int* __restrict__ cnts,
        const int* __restrict__ flag,
        u16* __restrict__ kb, u16* __restrict__ qb, u16* __restrict__ vb) {
    int f = *flag;
    int tt = blockIdx.x % TN, tile = blockIdx.x / TN;
    int cnt = cnts[tt];
    int start = tile * 64;
    if (start >= cnt) return;
    __shared__ int nl[64];
    __shared__ __align__(16) u16 xs[64][280];
    __shared__ __align__(16) float bias_s[768];
    int t = threadIdx.x;
    if (t < 64) nl[t] = (start + t < cnt) ? lists[tt * NN + start + t] : -1;
    if (t < 256) {
        bias_s[t]       = ld(bk, tt * 256 + t, f);
        bias_s[256 + t] = ld(bq, tt * 256 + t, f);
        bias_s[512 + t] = ld(bv, tt * 256 + t, f);
    }
    __syncthreads();
    {
        int i = t >> 4, g = t & 15;
        #pragma unroll
        for (int i2 = 0; i2 < 2; ++i2) {
            int row = i + i2 * 32;
            int node = nl[row];
            uint4 a = {0, 0, 0, 0}, b = {0, 0, 0, 0};
            if (node >= 0) {
                const uint4* src = (const uint4*)(xb + (size_t)node * 256 + g * 16);
                a = src[0]; b = src[1];
            }
            *(uint4*)&xs[row][g * 16] = a;
            *(uint4*)&xs[row][g * 16 + 8] = b;
        }
    }
    __syncthreads();
    int w = t >> 6, lane = t & 63, ln = lane & 15, quad = lane >> 4;
    const u16* Wt = WallT + (size_t)tt * 768 * 256;
    f32x4 acc[6][4];
    #pragma unroll
    for (int j = 0; j < 6; ++j)
        #pragma unroll
        for (int g = 0; g < 4; ++g)
            acc[j][g] = (f32x4){0.f, 0.f, 0.f, 0.f};
    for (int kt = 0; kt < 8; ++kt) {
        bf16x8 A[6];
        #pragma unroll
        for (int jt = 0; jt < 6; ++jt)
            A[jt] = *(const bf16x8*)(Wt + (size_t)(w * 96 + jt * 16 + ln) * 256 + kt * 32 + quad * 8);
        bf16x8 B[4];
        #pragma unroll
        for (int g = 0; g < 4; ++g)
            B[g] = *(const bf16x8*)&xs[g * 16 + ln][kt * 32 + quad * 8];
        #pragma unroll
        for (int jt = 0; jt < 6; ++jt)
            #pragma unroll
            for (int g = 0; g < 4; ++g)
                acc[jt][g] = __builtin_amdgcn_mfma_f32_16x16x32_bf16(A[jt], B[g], acc[jt][g], 0, 0, 0);
    }
    #pragma unroll
    for (int jt = 0; jt < 6; ++jt) {
        int jc = w * 96 + jt * 16 + quad * 4;
        float4 bi = *(const float4*)&bias_s[jc];
        int sec = jc >> 8, o = jc & 255;
        u16* basep = (sec == 0 ? kb : sec == 1 ? qb : vb);
        #pragma unroll
        for (int g = 0; g < 4; ++g) {
            int node = nl[g * 16 + ln];
            if (node >= 0) {
                ushort4 p;
                p.x = f2us(acc[jt][g][0] + bi.x); p.y = f2us(acc[jt][g][1] + bi.y);
                p.z = f2us(acc[jt][g][2] + bi.z); p.w = f2us(acc[jt][g][3] + bi.w);
                *(ushort4*)(basep + (size_t)node * 256 + o) = p;
            }
        }
    }
}

// ---------------- fused attention + aggregation, r-loop in block ----------------
// grid NN/CD = 3125; block = 16 consecutive dsts, loops r=0..5.
// qL: staged q rows (persistent). qrs: qrel (ph0.5-A) then sraw (phB-C).
// phB: wave covers 2 dsts (half-wave each, 16B vb loads). accF[4] registers
// accumulate MTm@sraw across relations; one float4 store per dst at end.
__global__ __launch_bounds__(256) void k2k4(const u16* __restrict__ kb,
        const u16* __restrict__ qb, const u16* __restrict__ vb,
        const u16* __restrict__ MTa, const u16* __restrict__ MTm,
        const void* __restrict__ rel_pri,
        const int* __restrict__ sorted, const int* __restrict__ base,
        const int* __restrict__ esrc, const int* __restrict__ edst,
        const int* __restrict__ flag,
        u16* __restrict__ attex_g, float* __restrict__ tacc) {
    int f = *flag;
    int c0 = blockIdx.x * CD;
    int nd = min(CD, NN - c0);       // always 16 (50000 = 3125*16)
    __shared__ float attL[LCAP];     // first LCAP/4 edges' exp (edge-heads)
    __shared__ int srcL[LCAP];       // first LCAP edges' src
    __shared__ float denomL[CD * HN];
    __shared__ int sb_[CD + 1];
    __shared__ __align__(16) u16 qL[CD][264];
    __shared__ __align__(16) u16 qrs[CD][264];
    int t = threadIdx.x;
    int w = t >> 6, lane = t & 63, ln = lane & 15, quad = lane >> 4;
    // stage q rows ONCE (16 threads per row, 32B each)
    {
        int i = t >> 4, g = t & 15;
        uint4 a0 = {0,0,0,0}, a1 = {0,0,0,0};
        if (i < nd) {
            const uint4* src = (const uint4*)(qb + (size_t)(c0 + i) * 256 + g * 16);
            a0 = src[0]; a1 = src[1];
        }
        *(uint4*)&qL[i][g * 16] = a0;
        *(uint4*)&qL[i][g * 16 + 8] = a1;
    }
    f32x4 accF[4];
    #pragma unroll
    for (int m = 0; m < 4; ++m) accF[m] = (f32x4){0.f, 0.f, 0.f, 0.f};

    for (int r = 0; r < RN; ++r) {
        if (t < CD * HN) denomL[t] = 0.f;
        if (t <= nd) sb_[t] = base[r * NN + c0 + t];
        __syncthreads();   // S1: sb/denom ready; prev phase C done with qrs; qL ready (r=0)
        long mtbase = (long)(r * HN + w) * 4096;
        // phase 0.5: qrs := qrel = MTa[r] @ qL   (wave = head, rows = ln)
        {
            bf16x8 B0 = *(const bf16x8*)&qL[ln][w * 64 + quad * 8];
            bf16x8 B1 = *(const bf16x8*)&qL[ln][w * 64 + quad * 8 + 32];
            #pragma unroll
            for (int mt = 0; mt < 4; ++mt) {
                const u16* ap = MTa + mtbase + (mt * 16 + ln) * 64 + quad * 8;
                bf16x8 A0 = *(const bf16x8*)(ap);
                bf16x8 A1 = *(const bf16x8*)(ap + 32);
                f32x4 acc = {0.f, 0.f, 0.f, 0.f};
                acc = __builtin_amdgcn_mfma_f32_16x16x32_bf16(A0, B0, acc, 0, 0, 0);
                acc = __builtin_amdgcn_mfma_f32_16x16x32_bf16(A1, B1, acc, 0, 0, 0);
                int jc = w * 64 + mt * 16 + quad * 4;
                ushort4 pq;
                pq.x = f2us(acc[0]); pq.y = f2us(acc[1]);
                pq.z = f2us(acc[2]); pq.w = f2us(acc[3]);
                *(ushort4*)&qrs[ln][jc] = pq;
            }
        }
        __syncthreads();   // S2: qrel ready
        int b0 = sb_[0], nE = sb_[nd] - b0;
        // phase A: att logits -> exp (thread per edge-head)
        for (int i = t; i < nE * 4; i += 256) {
            int ei = i >> 2;
            int e = sorted[b0 + ei];
            int h = i & 3;
            int s = esrc[e], dv = edst[e] - c0;
            if (h == 0 && ei < LCAP) srcL[ei] = s;
            const uint4* kp = (const uint4*)(kb + (size_t)s * 256 + h * 64);
            const uint4* qp = (const uint4*)&qrs[dv][h * 64];
            float dot = 0.f;
            #pragma unroll
            for (int ii = 0; ii < 8; ++ii) {
                uint4 a = kp[ii], b = qp[ii];
                dot += blo(a.x) * blo(b.x) + bhi(a.x) * bhi(b.x);
                dot += blo(a.y) * blo(b.y) + bhi(a.y) * bhi(b.y);
                dot += blo(a.z) * blo(b.z) + bhi(a.z) * bhi(b.z);
                dot += blo(a.w) * blo(b.w) + bhi(a.w) * bhi(b.w);
            }
            float attv = dot * ld(rel_pri, r * HN + h, f) * 0.125f;
            attv = fminf(fmaxf(attv, -50.f), 50.f);
            float ex = expf(attv);
            if (i < LCAP) attL[i] = ex;
            else attex_g[(size_t)b0 * 4 + i] = f2us(ex);   // rare spill path
            atomicAdd(&denomL[dv * HN + h], ex);
        }
        __syncthreads();   // S3: denom ready, qrel dead
        // phase B: qrs := sraw (wave covers 2 dsts; half-wave per dst; 8 dims/lane)
        {
            int half = lane >> 5, lane32 = lane & 31;
            int h = lane32 >> 3;   // 8 lanes per head, 8 dims per lane
            for (int i2 = w * 2 + half; i2 < nd; i2 += 8) {
                int sb = sb_[i2], se = sb_[i2 + 1];
                float a0=0.f,a1=0.f,a2=0.f,a3=0.f,a4=0.f,a5=0.f,a6=0.f,a7=0.f;
                if (se > sb) {
                    float inv = 1.f / denomL[i2 * HN + h];
                    for (int idx = sb; idx < se; ++idx) {
                        int rel = idx - b0;
                        int li2 = rel * 4 + h;
                        float wgt = ((li2 < LCAP) ? attL[li2]
                                     : busf(attex_g[(size_t)idx * 4 + h])) * inv;
                        int s = (rel < LCAP) ? srcL[rel] : esrc[sorted[idx]];
                        uint4 v = *(const uint4*)(vb + (size_t)s * 256 + lane32 * 8);
                        a0 += wgt * blo(v.x); a1 += wgt * bhi(v.x);
                        a2 += wgt * blo(v.y); a3 += wgt * bhi(v.y);
                        a4 += wgt * blo(v.z); a5 += wgt * bhi(v.z);
                        a6 += wgt * blo(v.w); a7 += wgt * bhi(v.w);
                    }
                }
                u16 pv8[8];
                pv8[0]=f2us(a0); pv8[1]=f2us(a1); pv8[2]=f2us(a2); pv8[3]=f2us(a3);
                pv8[4]=f2us(a4); pv8[5]=f2us(a5); pv8[6]=f2us(a6); pv8[7]=f2us(a7);
                *(uint4*)&qrs[i2][lane32 * 8] = *(const uint4*)pv8;
            }
        }
        __syncthreads();   // S4: sraw ready
        // phase C: accF += MTm[r] @ sraw  (register accumulation across r)
        {
            bf16x8 B0 = *(const bf16x8*)&qrs[ln][w * 64 + quad * 8];
            bf16x8 B1 = *(const bf16x8*)&qrs[ln][w * 64 + quad * 8 + 32];
            #pragma unroll
            for (int mt = 0; mt < 4; ++mt) {
                const u16* mp = MTm + mtbase + (mt * 16 + ln) * 64 + quad * 8;
                bf16x8 A0 = *(const bf16x8*)(mp);
                bf16x8 A1 = *(const bf16x8*)(mp + 32);
                accF[mt] = __builtin_amdgcn_mfma_f32_16x16x32_bf16(A0, B0, accF[mt], 0, 0, 0);
                accF[mt] = __builtin_amdgcn_mfma_f32_16x16x32_bf16(A1, B1, accF[mt], 0, 0, 0);
            }
        }
        // next iteration's S1 separates phase C reads from next phase 0.5 writes
    }
    // single tacc write (f32, no atomics)
    if (ln < nd) {
        #pragma unroll
        for (int mt = 0; mt < 4; ++mt) {
            int jc = w * 64 + mt * 16 + quad * 4;
            float4 v = {accF[mt][0], accF[mt][1], accF[mt][2], accF[mt][3]};
            *(float4*)(tacc + (long)(c0 + ln) * 256 + jc) = v;
        }
    }
}

// ---------------- fused out-linear (MFMA) + skip-gate + LayerNorm ----------------
__global__ __launch_bounds__(512, 4) void k5_fused(const void* __restrict__ x,
        const float* __restrict__ tacc, const u16* __restrict__ WaT,
        const void* __restrict__ ba, const void* __restrict__ skip,
        const void* __restrict__ ln_g, const void* __restrict__ ln_b,
        const int* __restrict__ base,
        const int* __restrict__ lists, const int* __restrict__ cnts,
        const int* __restrict__ flag, void* out) {
    int f = *flag;
    int tt = blockIdx.x % TN, tile = blockIdx.x / TN;
    int cnt = cnts[tt];
    int start = tile * 64;
    if (start >= cnt) return;
    __shared__ int nl[64];
    __shared__ float invs[64];
    __shared__ int hasv[64];
    __shared__ __align__(16) u16 xs[64][280];
    __shared__ __align__(16) float ba_s[256], lnG_s[256], lnB_s[256];
    __shared__ float red1[64][8], red2[64][8];
    __shared__ float mu_[64], rs_[64];
    int t = threadIdx.x;
    if (t < 64) {
        int node = (start + t < cnt) ? lists[tt * NN + start + t] : -1;
        nl[t] = node;
        int nrel = 0;
        if (node >= 0) {
            #pragma unroll
            for (int r = 0; r < RN; ++r)
                nrel += (base[r * NN + node + 1] > base[r * NN + node]) ? 1 : 0;
        }
        hasv[t] = nrel;
        invs[t] = (nrel > 0) ? 1.f / (float)nrel : 1.f;
    }
    if (t < 256) {
        ba_s[t]  = ld(ba,   tt * 256 + t, f);
        lnG_s[t] = ld(ln_g, tt * 256 + t, f);
        lnB_s[t] = ld(ln_b, tt * 256 + t, f);
    }
    __syncthreads();
    // gather tacc (f32) -> xs (bf16, pre-divided by nrel), vectorized
    {
        int i = t >> 3, g8 = t & 7;
        int node = nl[i];
        float inv = invs[i];
        int o0 = g8 * 32;
        u16 tmp[32];
        if (node >= 0) {
            const float* src = tacc + (long)node * 256 + o0;
            #pragma unroll
            for (int j = 0; j < 8; ++j) {
                float4 v = *(const float4*)(src + j * 4);
                tmp[j*4+0] = f2us(v.x * inv); tmp[j*4+1] = f2us(v.y * inv);
                tmp[j*4+2] = f2us(v.z * inv); tmp[j*4+3] = f2us(v.w * inv);
            }
        } else {
            #pragma unroll
            for (int j = 0; j < 32; ++j) tmp[j] = 0;
        }
        #pragma unroll
        for (int j = 0; j < 4; ++j)
            *(uint4*)&xs[i][o0 + j * 8] = ((const uint4*)tmp)[j];
    }
    __syncthreads();
    int w = t >> 6, lane = t & 63, ln = lane & 15, quad = lane >> 4;
    const u16* Wt = WaT + (size_t)tt * 65536;
    f32x4 acc[2][4];
    #pragma unroll
    for (int j = 0; j < 2; ++j)
        #pragma unroll
        for (int g = 0; g < 4; ++g)
            acc[j][g] = (f32x4){0.f, 0.f, 0.f, 0.f};
    for (int kt = 0; kt < 8; ++kt) {
        bf16x8 A[2];
        #pragma unroll
        for (int jt = 0; jt < 2; ++jt)
            A[jt] = *(const bf16x8*)(Wt + (size_t)(w * 32 + jt * 16 + ln) * 256 + kt * 32 + quad * 8);
        bf16x8 B[4];
        #pragma unroll
        for (int g = 0; g < 4; ++g)
            B[g] = *(const bf16x8*)&xs[g * 16 + ln][kt * 32 + quad * 8];
        #pragma unroll
        for (int jt = 0; jt < 2; ++jt)
            #pragma unroll
            for (int g = 0; g < 4; ++g)
                acc[jt][g] = __builtin_amdgcn_mfma_f32_16x16x32_bf16(A[jt], B[g], acc[jt][g], 0, 0, 0);
    }
    float sk = ld(skip, tt, f);
    float alpha = 1.f / (1.f + expf(-sk));
    float p1[4] = {0.f, 0.f, 0.f, 0.f}, p2[4] = {0.f, 0.f, 0.f, 0.f};
    #pragma unroll
    for (int g = 0; g < 4; ++g) {
        int node = nl[g * 16 + ln];
        if (node < 0) continue;
        #pragma unroll
        for (int jt = 0; jt < 2; ++jt) {
            int jc = w * 32 + jt * 16 + quad * 4;
            float4 bi = *(const float4*)&ba_s[jc];
            long xo = (long)node * 256 + jc;
            float xv[4];
            if (f) {
                float4 v = *(const float4*)((const float*)x + xo);
                xv[0] = v.x; xv[1] = v.y; xv[2] = v.z; xv[3] = v.w;
            } else {
                ushort4 v = *(const ushort4*)((const u16*)x + xo);
                xv[0] = busf(v.x); xv[1] = busf(v.y); xv[2] = busf(v.z); xv[3] = busf(v.w);
            }
            #pragma unroll
            for (int rg = 0; rg < 4; ++rg) {
                float ov = acc[jt][g][rg] + ((const float*)&bi)[rg];
                ov = ov * alpha + xv[rg] * (1.f - alpha);
                acc[jt][g][rg] = ov;
                p1[g] += ov; p2[g] += ov * ov;
            }
        }
    }
    #pragma unroll
    for (int g = 0; g < 4; ++g) {
        p1[g] += __shfl_xor(p1[g], 16); p1[g] += __shfl_xor(p1[g], 32);
        p2[g] += __shfl_xor(p2[g], 16); p2[g] += __shfl_xor(p2[g], 32);
    }
    if (quad == 0) {
        #pragma unroll
        for (int g = 0; g < 4; ++g) {
            red1[g * 16 + ln][w] = p1[g];
            red2[g * 16 + ln][w] = p2[g];
        }
    }
    __syncthreads();
    if (t < 64) {
        float s1 = 0.f, s2 = 0.f;
        #pragma unroll
        for (int j = 0; j < 8; ++j) { s1 += red1[t][j]; s2 += red2[t][j]; }
        float mu = s1 * (1.f / 256.f);
        float ms = s2 * (1.f / 256.f);
        float var = fmaxf(ms - mu * mu, 0.f);
        mu_[t] = mu; rs_[t] = rsqrtf(var + 1e-5f);
    }
    __syncthreads();
    #pragma unroll
    for (int g = 0; g < 4; ++g) {
        int li = g * 16 + ln;
        int node = nl[li];
        if (node < 0) continue;
        if (hasv[li] > 0) {
            float mu = mu_[li], rs = rs_[li];
            #pragma unroll
            for (int jt = 0; jt < 2; ++jt) {
                int jc = w * 32 + jt * 16 + quad * 4;
                float4 gg = *(const float4*)&lnG_s[jc];
                float4 bb = *(const float4*)&lnB_s[jc];
                long oo = (long)node * 256 + jc;
                float r0 = (acc[jt][g][0] - mu) * rs * gg.x + bb.x;
                float r1 = (acc[jt][g][1] - mu) * rs * gg.y + bb.y;
                float r2 = (acc[jt][g][2] - mu) * rs * gg.z + bb.z;
                float r3 = (acc[jt][g][3] - mu) * rs * gg.w + bb.w;
                if (f) { float4 v = {r0, r1, r2, r3}; *(float4*)((float*)out + oo) = v; }
                else   { ushort4 v; v.x = f2us(r0); v.y = f2us(r1); v.z = f2us(r2); v.w = f2us(r3);
                         *(ushort4*)((u16*)out + oo) = v; }
            }
        } else {
            #pragma unroll
            for (int jt = 0; jt < 2; ++jt) {
                int jc = w * 32 + jt * 16 + quad * 4;
                long oo = (long)node * 256 + jc;
                if (f) { *(float4*)((float*)out + oo) = *(const float4*)((const float*)x + oo); }
                else   { *(ushort4*)((u16*)out + oo) = *(const ushort4*)((const u16*)x + oo); }
            }
        }
    }
}

extern "C" void kernel_launch(void* const* d_in, const int* in_sizes, int n_in,
                              void* d_out, int out_size, void* d_ws, size_t ws_size,
                              hipStream_t stream) {
    const void* x       = d_in[0];
    const void* Wk      = d_in[1];
    const void* bk      = d_in[2];
    const void* Wq      = d_in[3];
    const void* bq      = d_in[4];
    const void* Wv      = d_in[5];
    const void* bv      = d_in[6];
    const void* Wa      = d_in[7];
    const void* ba      = d_in[8];
    const void* rel_pri = d_in[9];
    const void* rel_att = d_in[10];
    const void* rel_msg = d_in[11];
    const void* skip    = d_in[12];
    const void* ln_g    = d_in[13];
    const void* ln_b    = d_in[14];
    const int* node_type = (const int*)d_in[15];
    const int* edge_src  = (const int*)d_in[16];
    const int* edge_dst  = (const int*)d_in[17];
    const int* edge_type = (const int*)d_in[18];
    char* w = (char*)d_ws;

    // layout (bytes) — total 137,767,552 <= proven ws floor 141,000,128
    u16*      kb     = (u16*)(w);                    // 25,600,000
    u16*      qb     = (u16*)(w + 25600000);         // 25,600,000
    u16*      vb     = (u16*)(w + 51200000);         // 25,600,000
    float*    tacc   = (float*)(w + 76800000);       // 51,200,000 (f32; xb overlay first)
    u16*      xb     = (u16*)(w + 76800000);         //   overlay (consumed by k1)
    u16*      attex  = (u16*)(w + 128000000);        //  3,200,000
    int*      sorted = (int*)(w + 131200000);        //  1,600,000
    int*      base   = (int*)(w + 132800000);        //  1,200,064
    int*      nlists = (int*)(w + 134000064);        //    600,000
    u16*      MTa    = (u16*)(w + 134600064);        //    196,608
    u16*      MTm    = (u16*)(w + 134796672);        //    196,608
    u16*      WallT  = (u16*)(w + 134993280);        //  1,179,648
    u16*      WaT    = (u16*)(w + 136172928);        //    393,216
    // zero region:
    unsigned* cnt    = (unsigned*)(w + 136566144);   //  1,200,000
    int*      ncnts  = (int*)(w + 137766144);        //         64
    int*      flag   = (int*)(w + 137766208);        //         64
    unsigned* csums  = (unsigned*)(w + 137766272);   //      1,280

    hipMemsetAsync(w + 136566144, 0, 1201408, stream);

    detect_dtype<<<dim3(1), dim3(256), 0, stream>>>(x, flag);
    prep<<<dim3(17379), dim3(256), 0, stream>>>(
        rel_att, rel_msg, Wk, Wq, Wv, Wa, x, node_type, edge_dst, edge_type,
        flag, MTa, MTm, WallT, WaT, xb, nlists, ncnts, cnt);
    scanA<<<dim3(NCHUNK), dim3(256), 0, stream>>>(cnt, csums);
    scanB<<<dim3(1), dim3(256), 0, stream>>>(csums, base);
    scanC<<<dim3(NCHUNK), dim3(256), 0, stream>>>(cnt, csums, base);
    scatter_edges<<<dim3((EE + 255) / 256), dim3(256), 0, stream>>>(
        edge_dst, edge_type, base, cnt, sorted);

    k1_mfma<<<dim3(TN * ((NN + 63) / 64)), dim3(512), 0, stream>>>(
        xb, WallT, bk, bq, bv, nlists, ncnts, flag, kb, qb, vb);

    // tacc fully overwritten by k2k4 (register accumulation) -> no memset

    k2k4<<<dim3(NN / CD), dim3(256), 0, stream>>>(
        kb, qb, vb, MTa, MTm, rel_pri, sorted, base, edge_src, edge_dst,
        flag, attex, tacc);

    k5_fused<<<dim3(TN * ((NN + 63) / 64)), dim3(512), 0, stream>>>(
        x, tacc, WaT, ba, skip, ln_g, ln_b, base, nlists, ncnts, flag, d_out);
}